// Round 3
// baseline (32890.787 us; speedup 1.0000x reference)
//
#include <hip/hip_runtime.h>
#include <stdint.h>
#include <stddef.h>

#define B_ 16
#define T_ 1024
#define F_ 80
#define D_ 512
#define M_ 16384   // T*B rows, row index = t*16 + b
#define VO 29      // V+1

typedef float f32x4 __attribute__((ext_vector_type(4)));
typedef short s16x8 __attribute__((ext_vector_type(8)));
typedef unsigned short u16x8 __attribute__((ext_vector_type(8)));

static __device__ __forceinline__ unsigned short f2bf(float f) {
    union { float f; unsigned u; } v; v.f = f;
    unsigned r = v.u + 0x7FFFu + ((v.u >> 16) & 1u);
    return (unsigned short)(r >> 16);
}
static __device__ __forceinline__ float bf2f(unsigned short h) {
    union { unsigned u; float f; } v; v.u = ((unsigned)h) << 16; return v.f;
}
static __device__ __forceinline__ void split2(float v, unsigned short& hi, unsigned short& lo) {
    hi = f2bf(v);
    lo = f2bf(v - bf2f(hi));
}
static __device__ __forceinline__ float sigm(float x) {
    return 1.0f / (1.0f + __expf(-x));
}
static __device__ __forceinline__ float wred(float v) {
    #pragma unroll
    for (int off = 1; off < 64; off <<= 1) v += __shfl_xor(v, off, 64);
    return v;
}

// ---------------- weight conversion (fp32 -> bf16 hi/lo split) ----------------
// sru_w0 (80,2048) -> [2048][96] hi/lo, zero-padded K 80->96
__global__ __launch_bounds__(256) void conv_w0(const float* __restrict__ W,
        unsigned short* __restrict__ Bh, unsigned short* __restrict__ Bl) {
    int gid = blockIdx.x * 256 + threadIdx.x;     // 2048*96
    int n = gid / 96, k = gid - n * 96;
    float v = (k < 80) ? W[(size_t)k * 2048 + n] : 0.0f;
    unsigned short h, l; split2(v, h, l);
    Bh[gid] = h; Bl[gid] = l;
}
// one SRU layer: W (512,1536) -> (1536,512) hi/lo (transpose)
__global__ __launch_bounds__(256) void conv_sruw1(const float* __restrict__ W,
        unsigned short* __restrict__ Bh, unsigned short* __restrict__ Bl) {
    int gid = blockIdx.x * 256 + threadIdx.x;     // 1536*512
    int n = gid >> 9, k = gid & 511;
    float v = W[(size_t)k * 1536 + n];
    unsigned short h, lo; split2(v, h, lo);
    Bh[gid] = h; Bl[gid] = lo;
}
// row-major cast+split (already in Bt layout)
__global__ __launch_bounds__(256) void conv_split(const float* __restrict__ W,
        unsigned short* __restrict__ Oh, unsigned short* __restrict__ Ol, int n) {
    int gid = blockIdx.x * 256 + threadIdx.x;
    if (gid < n) {
        unsigned short h, l; split2(W[gid], h, l);
        Oh[gid] = h; Ol[gid] = l;
    }
}
__global__ void zero_cnt(unsigned int* c) { if (threadIdx.x < 8) c[threadIdx.x] = 0u; }

// ---------------- LayerNorm kernels ----------------
// LN over F=80 with (B,T,F)->(T*B,96) transpose, hi/lo bf16 out zero-padded to 96
__global__ __launch_bounds__(256) void ln80_kernel(const float* __restrict__ x,
        const float* __restrict__ g, const float* __restrict__ bta,
        unsigned short* __restrict__ xh, unsigned short* __restrict__ xl) {
    int w = threadIdx.x >> 6, lane = threadIdx.x & 63;
    int row = blockIdx.x * 4 + w;          // row = t*16 + b
    int b = row & 15, t = row >> 4;
    const float* xr = x + ((size_t)b * T_ + t) * F_;
    float v0 = xr[lane];
    float v1 = (lane < 16) ? xr[64 + lane] : 0.0f;
    float mean = wred(v0 + v1) * (1.0f / 80.0f);
    float d0 = v0 - mean;
    float d1 = (lane < 16) ? (v1 - mean) : 0.0f;
    float var = wred(d0 * d0 + d1 * d1) * (1.0f / 80.0f);
    float rstd = rsqrtf(var + 1e-5f);
    float o0 = d0 * rstd * g[lane] + bta[lane];
    unsigned short h, l; split2(o0, h, l);
    xh[(size_t)row * 96 + lane] = h;
    xl[(size_t)row * 96 + lane] = l;
    if (lane < 32) {
        unsigned short hv = 0, lv = 0;
        if (lane < 16) {
            float o1 = d1 * rstd * g[64 + lane] + bta[64 + lane];
            split2(o1, hv, lv);
        }
        xh[(size_t)row * 96 + 64 + lane] = hv;
        xl[(size_t)row * 96 + 64 + lane] = lv;
    }
}

// LN over D=512 -> bf16 hi/lo
__global__ __launch_bounds__(256) void ln512_bf16(const float* __restrict__ hsrc,
        const float* __restrict__ g, const float* __restrict__ bta,
        unsigned short* __restrict__ oh, unsigned short* __restrict__ ol) {
    int w = threadIdx.x >> 6, lane = threadIdx.x & 63;
    size_t row = (size_t)blockIdx.x * 4 + w;
    const float* hr = hsrc + row * D_;
    float4 p0 = *(const float4*)(hr + lane * 8);
    float4 p1 = *(const float4*)(hr + lane * 8 + 4);
    float s = p0.x + p0.y + p0.z + p0.w + p1.x + p1.y + p1.z + p1.w;
    float mean = wred(s) * (1.0f / 512.0f);
    float d[8] = {p0.x - mean, p0.y - mean, p0.z - mean, p0.w - mean,
                  p1.x - mean, p1.y - mean, p1.z - mean, p1.w - mean};
    float q = 0.f;
    #pragma unroll
    for (int i = 0; i < 8; ++i) q += d[i] * d[i];
    float rstd = rsqrtf(wred(q) * (1.0f / 512.0f) + 1e-5f);
    const float* gp = g + lane * 8;
    const float* bp = bta + lane * 8;
    u16x8 vh, vl;
    #pragma unroll
    for (int i = 0; i < 8; ++i) {
        float o = d[i] * rstd * gp[i] + bp[i];
        unsigned short hh, ll; split2(o, hh, ll);
        vh[i] = hh; vl[i] = ll;
    }
    *(u16x8*)(oh + row * D_ + lane * 8) = vh;
    *(u16x8*)(ol + row * D_ + lane * 8) = vl;
}

// LN over D=512 -> fp32 (classifier input)
__global__ __launch_bounds__(256) void ln512_f32(const float* __restrict__ hsrc,
        const float* __restrict__ g, const float* __restrict__ bta,
        float* __restrict__ o) {
    int w = threadIdx.x >> 6, lane = threadIdx.x & 63;
    size_t row = (size_t)blockIdx.x * 4 + w;
    const float* hr = hsrc + row * D_;
    float4 p0 = *(const float4*)(hr + lane * 8);
    float4 p1 = *(const float4*)(hr + lane * 8 + 4);
    float s = p0.x + p0.y + p0.z + p0.w + p1.x + p1.y + p1.z + p1.w;
    float mean = wred(s) * (1.0f / 512.0f);
    float d[8] = {p0.x - mean, p0.y - mean, p0.z - mean, p0.w - mean,
                  p1.x - mean, p1.y - mean, p1.z - mean, p1.w - mean};
    float q = 0.f;
    #pragma unroll
    for (int i = 0; i < 8; ++i) q += d[i] * d[i];
    float rstd = rsqrtf(wred(q) * (1.0f / 512.0f) + 1e-5f);
    const float* gp = g + lane * 8;
    const float* bp = bta + lane * 8;
    float* op = o + row * D_ + lane * 8;
    #pragma unroll
    for (int i = 0; i < 8; ++i) op[i] = d[i] * rstd * gp[i] + bp[i];
}

// ------- split bf16 MFMA GEMM (fp32-accurate): C = A * Bt^T (+bias0+bias1) -------
// A given as hi/lo [M][Kp], Bt as hi/lo [N][Kp]. C fp32 [M][N].
__global__ __launch_bounds__(256) void gemm_split(
        const unsigned short* __restrict__ Ah, const unsigned short* __restrict__ Al,
        const unsigned short* __restrict__ Bh, const unsigned short* __restrict__ Bl,
        float* __restrict__ C, int N, int Kp,
        const float* __restrict__ bias0, const float* __restrict__ bias1) {
    __shared__ __align__(16) unsigned short sAh[64][40];
    __shared__ __align__(16) unsigned short sAl[64][40];
    __shared__ __align__(16) unsigned short sBh[64][40];
    __shared__ __align__(16) unsigned short sBl[64][40];
    int tid = threadIdx.x;
    int w = tid >> 6, lane = tid & 63;
    int r_ = lane >> 4, c_ = lane & 15;
    int mBase = blockIdx.y * 64, nBase = blockIdx.x * 64;
    int srow = tid >> 2, sseg = (tid & 3) * 8;
    const unsigned short* gAh = Ah + (size_t)(mBase + srow) * Kp + sseg;
    const unsigned short* gAl = Al + (size_t)(mBase + srow) * Kp + sseg;
    const unsigned short* gBh = Bh + (size_t)(nBase + srow) * Kp + sseg;
    const unsigned short* gBl = Bl + (size_t)(nBase + srow) * Kp + sseg;
    f32x4 acc[4] = {{0.f,0.f,0.f,0.f},{0.f,0.f,0.f,0.f},{0.f,0.f,0.f,0.f},{0.f,0.f,0.f,0.f}};
    for (int kt = 0; kt < Kp; kt += 32) {
        *(u16x8*)&sAh[srow][sseg] = *(const u16x8*)(gAh + kt);
        *(u16x8*)&sAl[srow][sseg] = *(const u16x8*)(gAl + kt);
        *(u16x8*)&sBh[srow][sseg] = *(const u16x8*)(gBh + kt);
        *(u16x8*)&sBl[srow][sseg] = *(const u16x8*)(gBl + kt);
        __syncthreads();
        s16x8 ah = *(const s16x8*)&sAh[w * 16 + c_][r_ * 8];
        s16x8 al = *(const s16x8*)&sAl[w * 16 + c_][r_ * 8];
        #pragma unroll
        for (int nt = 0; nt < 4; ++nt) {
            s16x8 bh = *(const s16x8*)&sBh[nt * 16 + c_][r_ * 8];
            s16x8 bl = *(const s16x8*)&sBl[nt * 16 + c_][r_ * 8];
            acc[nt] = __builtin_amdgcn_mfma_f32_16x16x32_bf16(ah, bh, acc[nt], 0, 0, 0);
            acc[nt] = __builtin_amdgcn_mfma_f32_16x16x32_bf16(al, bh, acc[nt], 0, 0, 0);
            acc[nt] = __builtin_amdgcn_mfma_f32_16x16x32_bf16(ah, bl, acc[nt], 0, 0, 0);
        }
        __syncthreads();
    }
    #pragma unroll
    for (int r = 0; r < 4; ++r) {
        int m = mBase + w * 16 + r_ * 4 + r;
        float* crow = C + (size_t)m * N + nBase;
        #pragma unroll
        for (int nt = 0; nt < 4; ++nt) {
            int n = nBase + nt * 16 + c_;
            float bb = 0.f;
            if (bias0) bb += bias0[n];
            if (bias1) bb += bias1[n];
            crow[nt * 16 + c_] = acc[nt][r] + bb;
        }
    }
}

// ---------------- SRU recurrence: 8192 independent (b,d) chains ----------------
__global__ __launch_bounds__(64) void sru_rec(const float* __restrict__ U, int NU,
        const float* __restrict__ xprev, const float* __restrict__ wc,
        const float* __restrict__ bias, float* __restrict__ hout) {
    int gid = blockIdx.x * 64 + threadIdx.x;
    int d = gid & (D_ - 1), b = gid >> 9;
    float vf = wc[d], vr = wc[D_ + d];
    float bf = bias[d], br = bias[D_ + d];
    const float* u0 = U + d;
    const float* u1 = U + D_ + d;
    const float* u2 = U + 2 * D_ + d;
    const float* xr;  size_t xstride;
    if (xprev) { xr = xprev + d; xstride = D_; }
    else       { xr = U + 3 * (size_t)D_ + d; xstride = (size_t)NU; }
    float* ho = hout + d;
    float c = 0.f;
    #pragma unroll 4
    for (int t = 0; t < T_; ++t) {
        size_t row = (size_t)(t * 16 + b);
        float a0 = u0[row * NU];
        float a1 = u1[row * NU];
        float a2 = u2[row * NU];
        float xv = xr[row * xstride];
        float f = sigm(a1 + vf * c + bf);
        float r = sigm(a2 + vr * c + br);
        c = f * c + (1.f - f) * a0;
        float h = r * c + (1.f - r) * xv;
        ho[row * D_] = h;
    }
}

// ---------------- LSTM recurrence: 16-WG persistent cooperative kernel ------------
// WG wg owns dims [wg*32, wg*32+32). Wave w computes gate w for those dims.
// whh hi/lo slices in VGPRs (256 regs); h broadcast as bf16 hi/lo packs via global
// double buffer + agent-scope counter barrier. 3-term split MFMA = fp32-accurate.
__global__ __launch_bounds__(256, 1) void lstm_rec(const float* __restrict__ gx,
        const unsigned short* __restrict__ Wh, const unsigned short* __restrict__ Wl,
        float* __restrict__ hout,
        unsigned int* __restrict__ hbuf /*2 phases x {hi[4096], lo[4096]}*/,
        unsigned int* __restrict__ cnt) {
    __shared__ __align__(16) unsigned short hH[16][520];
    __shared__ __align__(16) unsigned short hL[16][520];
    __shared__ float G[16][132];
    int tid = threadIdx.x;
    int w = tid >> 6, lane = tid & 63;
    int wg = blockIdx.x;
    int c_ = lane & 15, r_ = lane >> 4;

    s16x8 bh0[16], bh1[16], bl0[16], bl1[16];
    {
        size_t R0 = (size_t)(w * 512 + wg * 32 + c_) * 512;
        size_t R1 = R0 + 16 * 512;
        #pragma unroll
        for (int ks = 0; ks < 16; ++ks) {
            bh0[ks] = *(const s16x8*)(Wh + R0 + ks * 32 + r_ * 8);
            bh1[ks] = *(const s16x8*)(Wh + R1 + ks * 32 + r_ * 8);
            bl0[ks] = *(const s16x8*)(Wl + R0 + ks * 32 + r_ * 8);
            bl1[ks] = *(const s16x8*)(Wl + R1 + ks * 32 + r_ * 8);
        }
    }
    for (int i = tid; i < 16 * 520; i += 256) {
        ((unsigned short*)hH)[i] = 0;
        ((unsigned short*)hL)[i] = 0;
    }
    int eb = tid >> 4;
    int ed = (tid * 2) & 31;
    float cc0 = 0.f, cc1 = 0.f;
    __syncthreads();

    for (int t = 0; t < T_; ++t) {
        f32x4 acc0 = {0.f, 0.f, 0.f, 0.f};
        f32x4 acc1 = {0.f, 0.f, 0.f, 0.f};
        #pragma unroll
        for (int ks = 0; ks < 16; ++ks) {
            s16x8 ah = *(const s16x8*)&hH[c_][ks * 32 + r_ * 8];
            s16x8 al = *(const s16x8*)&hL[c_][ks * 32 + r_ * 8];
            acc0 = __builtin_amdgcn_mfma_f32_16x16x32_bf16(ah, bh0[ks], acc0, 0, 0, 0);
            acc1 = __builtin_amdgcn_mfma_f32_16x16x32_bf16(ah, bh1[ks], acc1, 0, 0, 0);
            acc0 = __builtin_amdgcn_mfma_f32_16x16x32_bf16(al, bh0[ks], acc0, 0, 0, 0);
            acc1 = __builtin_amdgcn_mfma_f32_16x16x32_bf16(al, bh1[ks], acc1, 0, 0, 0);
            acc0 = __builtin_amdgcn_mfma_f32_16x16x32_bf16(ah, bl0[ks], acc0, 0, 0, 0);
            acc1 = __builtin_amdgcn_mfma_f32_16x16x32_bf16(ah, bl1[ks], acc1, 0, 0, 0);
        }
        const float* gxr = gx + (size_t)(t * 16) * 2048;
        int col0 = w * 512 + wg * 32 + c_;
        #pragma unroll
        for (int r = 0; r < 4; ++r) {
            int bt = r_ * 4 + r;
            G[bt][w * 32 + c_]      = acc0[r] + gxr[(size_t)bt * 2048 + col0];
            G[bt][w * 32 + 16 + c_] = acc1[r] + gxr[(size_t)bt * 2048 + col0 + 16];
        }
        __syncthreads();
        float iv0 = G[eb][ed],     fv0 = G[eb][32 + ed], gv0 = G[eb][64 + ed], ov0 = G[eb][96 + ed];
        float iv1 = G[eb][ed + 1], fv1 = G[eb][33 + ed], gv1 = G[eb][65 + ed], ov1 = G[eb][97 + ed];
        cc0 = sigm(fv0) * cc0 + sigm(iv0) * tanhf(gv0);
        cc1 = sigm(fv1) * cc1 + sigm(iv1) * tanhf(gv1);
        float h0 = sigm(ov0) * tanhf(cc0);
        float h1 = sigm(ov1) * tanhf(cc1);
        size_t orow = (size_t)(t * 16 + eb) * D_ + wg * 32 + ed;
        hout[orow] = h0; hout[orow + 1] = h1;
        unsigned short h0h, h0l, h1h, h1l;
        split2(h0, h0h, h0l); split2(h1, h1h, h1l);
        unsigned packH = (unsigned)h0h | ((unsigned)h1h << 16);
        unsigned packL = (unsigned)h0l | ((unsigned)h1l << 16);
        int bufs = ((t + 1) & 1) * 8192;
        int hidx = (eb * 512 + wg * 32 + ed) >> 1;
        __hip_atomic_store(&hbuf[bufs + hidx], packH, __ATOMIC_RELAXED, __HIP_MEMORY_SCOPE_AGENT);
        __hip_atomic_store(&hbuf[bufs + 4096 + hidx], packL, __ATOMIC_RELAXED, __HIP_MEMORY_SCOPE_AGENT);
        __threadfence();
        __syncthreads();     // all slice stores + fences done (also protects G reuse)
        if (tid == 0) {
            __hip_atomic_fetch_add(cnt, 1u, __ATOMIC_RELEASE, __HIP_MEMORY_SCOPE_AGENT);
            unsigned target = 16u * (unsigned)(t + 1);
            while (__hip_atomic_load(cnt, __ATOMIC_ACQUIRE, __HIP_MEMORY_SCOPE_AGENT) < target) {
                __builtin_amdgcn_s_sleep(2);
            }
        }
        __syncthreads();
        #pragma unroll
        for (int i = 0; i < 16; ++i) {
            int idx = i * 256 + tid;
            unsigned uh = __hip_atomic_load(&hbuf[bufs + idx], __ATOMIC_RELAXED, __HIP_MEMORY_SCOPE_AGENT);
            unsigned ul = __hip_atomic_load(&hbuf[bufs + 4096 + idx], __ATOMIC_RELAXED, __HIP_MEMORY_SCOPE_AGENT);
            int bb = idx >> 8;
            int kk = (idx & 255) * 2;
            *(unsigned*)&hH[bb][kk] = uh;
            *(unsigned*)&hL[bb][kk] = ul;
        }
        __syncthreads();
    }
}

// ---------------- classifier: out[b][t][v] = LN(h)[row] . cls_w[:,v] (fp32) ------
__global__ __launch_bounds__(256) void cls_gemm(const float* __restrict__ xn,
        const float* __restrict__ wcls, float* __restrict__ out) {
    __shared__ float wl[512][32];
    int tid = threadIdx.x;
    for (int idx = tid; idx < 512 * VO; idx += 256) {
        int k = idx / VO, v = idx - k * VO;
        wl[k][v] = wcls[idx];
    }
    __syncthreads();
    int r8 = tid >> 5, v = tid & 31;
    int row = blockIdx.x * 8 + r8;
    if (v >= VO) return;
    const float* xr = xn + (size_t)row * D_;
    float acc = 0.f;
    #pragma unroll 8
    for (int k = 0; k < 512; ++k) acc += xr[k] * wl[k][v];
    int b = row & 15, t = row >> 4;
    out[((size_t)b * T_ + t) * VO + v] = acc;
}

// ------------------------------- launch ------------------------------------------
// Workspace layout (~214 MB, fits conservative ws_size):
//   U  : M*1536 fp32 (100.7 MB)   -- SRU-layer GEMM out; [U|hP] = 2048-wide gx
//   hP : M*512 fp32 (33.5 MB)     -- adjacent to U (gx tail)
//   hQ : M*512 fp32 (33.5 MB)
//   xnh/xnl : M*512 bf16 planes (16.8 MB each)
//   per-layer reused weight buffers (hi/lo), hbuf, cnts
extern "C" void kernel_launch(void* const* d_in, const int* in_sizes, int n_in,
                              void* d_out, int out_size, void* d_ws, size_t ws_size,
                              hipStream_t stream) {
    const float* x        = (const float*)d_in[0];
    const float* sru_w0   = (const float*)d_in[1];
    const float* sru_wc0  = (const float*)d_in[2];
    const float* sru_b0   = (const float*)d_in[3];
    const float* sru_ln0g = (const float*)d_in[4];
    const float* sru_ln0b = (const float*)d_in[5];
    const float* sru_w    = (const float*)d_in[6];
    const float* sru_wc   = (const float*)d_in[7];
    const float* sru_b    = (const float*)d_in[8];
    const float* sru_lng  = (const float*)d_in[9];
    const float* sru_lnb  = (const float*)d_in[10];
    const float* lstm_lng = (const float*)d_in[11];
    const float* lstm_lnb = (const float*)d_in[12];
    const float* lstm_wih = (const float*)d_in[13];
    const float* lstm_whh = (const float*)d_in[14];
    const float* lstm_bih = (const float*)d_in[15];
    const float* lstm_bhh = (const float*)d_in[16];
    const float* cls_lng  = (const float*)d_in[17];
    const float* cls_lnb  = (const float*)d_in[18];
    const float* cls_w    = (const float*)d_in[19];
    float* out = (float*)d_out;

    char* ws = (char*)d_ws;
    size_t off = 0;
    auto alloc = [&](size_t bytes) -> void* {
        off = (off + 255) & ~(size_t)255;
        void* p = ws + off;
        off += bytes;
        return p;
    };
    float* U             = (float*)alloc((size_t)M_ * 1536 * 4);   // 100.7 MB
    float* hP            = (float*)alloc((size_t)M_ * D_ * 4);     // contiguous after U
    float* hQ            = (float*)alloc((size_t)M_ * D_ * 4);
    unsigned short* xnh  = (unsigned short*)alloc((size_t)M_ * D_ * 2);
    unsigned short* xnl  = (unsigned short*)alloc((size_t)M_ * D_ * 2);
    unsigned short* w0h  = (unsigned short*)alloc((size_t)2048 * 96 * 2);
    unsigned short* w0l  = (unsigned short*)alloc((size_t)2048 * 96 * 2);
    unsigned short* swh  = (unsigned short*)alloc((size_t)1536 * 512 * 2);  // per-layer reuse
    unsigned short* swl  = (unsigned short*)alloc((size_t)1536 * 512 * 2);
    unsigned short* wihh = (unsigned short*)alloc((size_t)2048 * 512 * 2);  // per-layer reuse
    unsigned short* wihl = (unsigned short*)alloc((size_t)2048 * 512 * 2);
    unsigned short* whhh = (unsigned short*)alloc((size_t)2048 * 512 * 2);  // per-layer reuse
    unsigned short* whhl = (unsigned short*)alloc((size_t)2048 * 512 * 2);
    unsigned int* hbuf   = (unsigned int*)alloc((size_t)2 * 2 * 4096 * 4);
    unsigned int* cnts   = (unsigned int*)alloc(8 * 4);
    float* gx = U;   // 2048-wide outputs span [U | hP] contiguously

    hipLaunchKernelGGL(zero_cnt, dim3(1), dim3(64), 0, stream, cnts);
    hipLaunchKernelGGL(conv_w0, dim3(768), dim3(256), 0, stream, sru_w0, w0h, w0l);

    // ---- SRU layer 0 (gx = [U|hP], output -> hQ) ----
    hipLaunchKernelGGL(ln80_kernel, dim3(4096), dim3(256), 0, stream, x, sru_ln0g, sru_ln0b, xnh, xnl);
    hipLaunchKernelGGL(gemm_split, dim3(2048 / 64, M_ / 64), dim3(256), 0, stream,
                       xnh, xnl, w0h, w0l, gx, 2048, 96, (const float*)nullptr, (const float*)nullptr);
    hipLaunchKernelGGL(sru_rec, dim3(128), dim3(64), 0, stream,
                       gx, 2048, (const float*)nullptr, sru_wc0, sru_b0, hQ);

    float* hcur = hQ; float* hnxt = hP;
    // ---- SRU layers 1..7 (GEMM writes U only; h ping-pongs hQ<->hP) ----
    for (int l = 0; l < 7; ++l) {
        hipLaunchKernelGGL(conv_sruw1, dim3(3072), dim3(256), 0, stream,
                           sru_w + (size_t)l * 512 * 1536, swh, swl);
        hipLaunchKernelGGL(ln512_bf16, dim3(4096), dim3(256), 0, stream,
                           hcur, sru_lng + (size_t)l * 512, sru_lnb + (size_t)l * 512, xnh, xnl);
        hipLaunchKernelGGL(gemm_split, dim3(1536 / 64, M_ / 64), dim3(256), 0, stream,
                           xnh, xnl, swh, swl, U, 1536, 512,
                           (const float*)nullptr, (const float*)nullptr);
        hipLaunchKernelGGL(sru_rec, dim3(128), dim3(64), 0, stream,
                           U, 1536, hcur, sru_wc + (size_t)l * 1024, sru_b + (size_t)l * 1024, hnxt);
        float* tmp = hcur; hcur = hnxt; hnxt = tmp;
    }
    // after 7 layers: hcur == hP (hQ->hP->hQ->hP->hQ->hP->hQ->hP)

    // ---- LSTM layers 0..2 (gx = [U|hP]; hP dead after its LN; out -> hQ in-place) ----
    for (int l = 0; l < 3; ++l) {
        hipLaunchKernelGGL(conv_split, dim3(4096), dim3(256), 0, stream,
                           lstm_wih + (size_t)l * 2048 * 512, wihh, wihl, 2048 * 512);
        hipLaunchKernelGGL(conv_split, dim3(4096), dim3(256), 0, stream,
                           lstm_whh + (size_t)l * 2048 * 512, whhh, whhl, 2048 * 512);
        hipLaunchKernelGGL(ln512_bf16, dim3(4096), dim3(256), 0, stream,
                           hcur, lstm_lng + (size_t)l * 512, lstm_lnb + (size_t)l * 512, xnh, xnl);
        hipLaunchKernelGGL(gemm_split, dim3(2048 / 64, M_ / 64), dim3(256), 0, stream,
                           xnh, xnl, wihh, wihl, gx, 2048, 512,
                           lstm_bih + (size_t)l * 2048, lstm_bhh + (size_t)l * 2048);
        hipLaunchKernelGGL(lstm_rec, dim3(16), dim3(256), 0, stream,
                           gx, whhh, whhl, hQ, hbuf, cnts + l);
        hcur = hQ;   // subsequent layers read/write hQ (dead after its LN)
    }
    // ---- classifier (LN fp32 into U region, then small GEMM) ----
    hipLaunchKernelGGL(ln512_f32, dim3(4096), dim3(256), 0, stream, hcur, cls_lng, cls_lnb, (float*)U);
    hipLaunchKernelGGL(cls_gemm, dim3(2048), dim3(256), 0, stream, (const float*)U, cls_w, out);
}

// Round 4
// 25268.146 us; speedup vs baseline: 1.3017x; 1.3017x over previous
//
#include <hip/hip_runtime.h>
#include <stdint.h>
#include <stddef.h>

#define B_ 16
#define T_ 1024
#define F_ 80
#define D_ 512
#define M_ 16384   // T*B rows, row index = t*16 + b
#define VO 29      // V+1

typedef float f32x4 __attribute__((ext_vector_type(4)));
typedef short s16x8 __attribute__((ext_vector_type(8)));
typedef unsigned short u16x8 __attribute__((ext_vector_type(8)));

static __device__ __forceinline__ unsigned short f2bf(float f) {
    union { float f; unsigned u; } v; v.f = f;
    unsigned r = v.u + 0x7FFFu + ((v.u >> 16) & 1u);
    return (unsigned short)(r >> 16);
}
static __device__ __forceinline__ float bf2f(unsigned short h) {
    union { unsigned u; float f; } v; v.u = ((unsigned)h) << 16; return v.f;
}
static __device__ __forceinline__ void split2(float v, unsigned short& hi, unsigned short& lo) {
    hi = f2bf(v);
    lo = f2bf(v - bf2f(hi));
}
static __device__ __forceinline__ float sigm(float x) {
    return 1.0f / (1.0f + __expf(-x));
}
static __device__ __forceinline__ float wred(float v) {
    #pragma unroll
    for (int off = 1; off < 64; off <<= 1) v += __shfl_xor(v, off, 64);
    return v;
}

// ---------------- weight conversion (fp32 -> bf16 hi/lo split) ----------------
// sru_w0 (80,2048) -> [2048][96] hi/lo, zero-padded K 80->96
__global__ __launch_bounds__(256) void conv_w0(const float* __restrict__ W,
        unsigned short* __restrict__ Bh, unsigned short* __restrict__ Bl) {
    int gid = blockIdx.x * 256 + threadIdx.x;     // 2048*96
    int n = gid / 96, k = gid - n * 96;
    float v = (k < 80) ? W[(size_t)k * 2048 + n] : 0.0f;
    unsigned short h, l; split2(v, h, l);
    Bh[gid] = h; Bl[gid] = l;
}
// one SRU layer: W (512,1536) -> (1536,512) hi/lo (transpose)
__global__ __launch_bounds__(256) void conv_sruw1(const float* __restrict__ W,
        unsigned short* __restrict__ Bh, unsigned short* __restrict__ Bl) {
    int gid = blockIdx.x * 256 + threadIdx.x;     // 1536*512
    int n = gid >> 9, k = gid & 511;
    float v = W[(size_t)k * 1536 + n];
    unsigned short h, lo; split2(v, h, lo);
    Bh[gid] = h; Bl[gid] = lo;
}
// row-major cast+split (already in Bt layout)
__global__ __launch_bounds__(256) void conv_split(const float* __restrict__ W,
        unsigned short* __restrict__ Oh, unsigned short* __restrict__ Ol, int n) {
    int gid = blockIdx.x * 256 + threadIdx.x;
    if (gid < n) {
        unsigned short h, l; split2(W[gid], h, l);
        Oh[gid] = h; Ol[gid] = l;
    }
}
__global__ void zero_cnt(unsigned int* c) { if (threadIdx.x < 8) c[threadIdx.x] = 0u; }

// ---------------- LayerNorm kernels ----------------
// LN over F=80 with (B,T,F)->(T*B,96) transpose, hi/lo bf16 out zero-padded to 96
__global__ __launch_bounds__(256) void ln80_kernel(const float* __restrict__ x,
        const float* __restrict__ g, const float* __restrict__ bta,
        unsigned short* __restrict__ xh, unsigned short* __restrict__ xl) {
    int w = threadIdx.x >> 6, lane = threadIdx.x & 63;
    int row = blockIdx.x * 4 + w;          // row = t*16 + b
    int b = row & 15, t = row >> 4;
    const float* xr = x + ((size_t)b * T_ + t) * F_;
    float v0 = xr[lane];
    float v1 = (lane < 16) ? xr[64 + lane] : 0.0f;
    float mean = wred(v0 + v1) * (1.0f / 80.0f);
    float d0 = v0 - mean;
    float d1 = (lane < 16) ? (v1 - mean) : 0.0f;
    float var = wred(d0 * d0 + d1 * d1) * (1.0f / 80.0f);
    float rstd = rsqrtf(var + 1e-5f);
    float o0 = d0 * rstd * g[lane] + bta[lane];
    unsigned short h, l; split2(o0, h, l);
    xh[(size_t)row * 96 + lane] = h;
    xl[(size_t)row * 96 + lane] = l;
    if (lane < 32) {
        unsigned short hv = 0, lv = 0;
        if (lane < 16) {
            float o1 = d1 * rstd * g[64 + lane] + bta[64 + lane];
            split2(o1, hv, lv);
        }
        xh[(size_t)row * 96 + 64 + lane] = hv;
        xl[(size_t)row * 96 + 64 + lane] = lv;
    }
}

// LN over D=512 -> bf16 hi/lo
__global__ __launch_bounds__(256) void ln512_bf16(const float* __restrict__ hsrc,
        const float* __restrict__ g, const float* __restrict__ bta,
        unsigned short* __restrict__ oh, unsigned short* __restrict__ ol) {
    int w = threadIdx.x >> 6, lane = threadIdx.x & 63;
    size_t row = (size_t)blockIdx.x * 4 + w;
    const float* hr = hsrc + row * D_;
    float4 p0 = *(const float4*)(hr + lane * 8);
    float4 p1 = *(const float4*)(hr + lane * 8 + 4);
    float s = p0.x + p0.y + p0.z + p0.w + p1.x + p1.y + p1.z + p1.w;
    float mean = wred(s) * (1.0f / 512.0f);
    float d[8] = {p0.x - mean, p0.y - mean, p0.z - mean, p0.w - mean,
                  p1.x - mean, p1.y - mean, p1.z - mean, p1.w - mean};
    float q = 0.f;
    #pragma unroll
    for (int i = 0; i < 8; ++i) q += d[i] * d[i];
    float rstd = rsqrtf(wred(q) * (1.0f / 512.0f) + 1e-5f);
    const float* gp = g + lane * 8;
    const float* bp = bta + lane * 8;
    u16x8 vh, vl;
    #pragma unroll
    for (int i = 0; i < 8; ++i) {
        float o = d[i] * rstd * gp[i] + bp[i];
        unsigned short hh, ll; split2(o, hh, ll);
        vh[i] = hh; vl[i] = ll;
    }
    *(u16x8*)(oh + row * D_ + lane * 8) = vh;
    *(u16x8*)(ol + row * D_ + lane * 8) = vl;
}

// LN over D=512 -> fp32 (classifier input)
__global__ __launch_bounds__(256) void ln512_f32(const float* __restrict__ hsrc,
        const float* __restrict__ g, const float* __restrict__ bta,
        float* __restrict__ o) {
    int w = threadIdx.x >> 6, lane = threadIdx.x & 63;
    size_t row = (size_t)blockIdx.x * 4 + w;
    const float* hr = hsrc + row * D_;
    float4 p0 = *(const float4*)(hr + lane * 8);
    float4 p1 = *(const float4*)(hr + lane * 8 + 4);
    float s = p0.x + p0.y + p0.z + p0.w + p1.x + p1.y + p1.z + p1.w;
    float mean = wred(s) * (1.0f / 512.0f);
    float d[8] = {p0.x - mean, p0.y - mean, p0.z - mean, p0.w - mean,
                  p1.x - mean, p1.y - mean, p1.z - mean, p1.w - mean};
    float q = 0.f;
    #pragma unroll
    for (int i = 0; i < 8; ++i) q += d[i] * d[i];
    float rstd = rsqrtf(wred(q) * (1.0f / 512.0f) + 1e-5f);
    const float* gp = g + lane * 8;
    const float* bp = bta + lane * 8;
    float* op = o + row * D_ + lane * 8;
    #pragma unroll
    for (int i = 0; i < 8; ++i) op[i] = d[i] * rstd * gp[i] + bp[i];
}

// ------- split bf16 MFMA GEMM (fp32-accurate): C = A * Bt^T (+bias0+bias1) -------
// A given as hi/lo [M][Kp], Bt as hi/lo [N][Kp]. C fp32 [M][N].
__global__ __launch_bounds__(256) void gemm_split(
        const unsigned short* __restrict__ Ah, const unsigned short* __restrict__ Al,
        const unsigned short* __restrict__ Bh, const unsigned short* __restrict__ Bl,
        float* __restrict__ C, int N, int Kp,
        const float* __restrict__ bias0, const float* __restrict__ bias1) {
    __shared__ __align__(16) unsigned short sAh[64][40];
    __shared__ __align__(16) unsigned short sAl[64][40];
    __shared__ __align__(16) unsigned short sBh[64][40];
    __shared__ __align__(16) unsigned short sBl[64][40];
    int tid = threadIdx.x;
    int w = tid >> 6, lane = tid & 63;
    int r_ = lane >> 4, c_ = lane & 15;
    int mBase = blockIdx.y * 64, nBase = blockIdx.x * 64;
    int srow = tid >> 2, sseg = (tid & 3) * 8;
    const unsigned short* gAh = Ah + (size_t)(mBase + srow) * Kp + sseg;
    const unsigned short* gAl = Al + (size_t)(mBase + srow) * Kp + sseg;
    const unsigned short* gBh = Bh + (size_t)(nBase + srow) * Kp + sseg;
    const unsigned short* gBl = Bl + (size_t)(nBase + srow) * Kp + sseg;
    f32x4 acc[4] = {{0.f,0.f,0.f,0.f},{0.f,0.f,0.f,0.f},{0.f,0.f,0.f,0.f},{0.f,0.f,0.f,0.f}};
    for (int kt = 0; kt < Kp; kt += 32) {
        *(u16x8*)&sAh[srow][sseg] = *(const u16x8*)(gAh + kt);
        *(u16x8*)&sAl[srow][sseg] = *(const u16x8*)(gAl + kt);
        *(u16x8*)&sBh[srow][sseg] = *(const u16x8*)(gBh + kt);
        *(u16x8*)&sBl[srow][sseg] = *(const u16x8*)(gBl + kt);
        __syncthreads();
        s16x8 ah = *(const s16x8*)&sAh[w * 16 + c_][r_ * 8];
        s16x8 al = *(const s16x8*)&sAl[w * 16 + c_][r_ * 8];
        #pragma unroll
        for (int nt = 0; nt < 4; ++nt) {
            s16x8 bh = *(const s16x8*)&sBh[nt * 16 + c_][r_ * 8];
            s16x8 bl = *(const s16x8*)&sBl[nt * 16 + c_][r_ * 8];
            acc[nt] = __builtin_amdgcn_mfma_f32_16x16x32_bf16(ah, bh, acc[nt], 0, 0, 0);
            acc[nt] = __builtin_amdgcn_mfma_f32_16x16x32_bf16(al, bh, acc[nt], 0, 0, 0);
            acc[nt] = __builtin_amdgcn_mfma_f32_16x16x32_bf16(ah, bl, acc[nt], 0, 0, 0);
        }
        __syncthreads();
    }
    #pragma unroll
    for (int r = 0; r < 4; ++r) {
        int m = mBase + w * 16 + r_ * 4 + r;
        float* crow = C + (size_t)m * N + nBase;
        #pragma unroll
        for (int nt = 0; nt < 4; ++nt) {
            int n = nBase + nt * 16 + c_;
            float bb = 0.f;
            if (bias0) bb += bias0[n];
            if (bias1) bb += bias1[n];
            crow[nt * 16 + c_] = acc[nt][r] + bb;
        }
    }
}

// ---------------- SRU recurrence: 8192 independent (b,d) chains ----------------
__global__ __launch_bounds__(64) void sru_rec(const float* __restrict__ U, int NU,
        const float* __restrict__ xprev, const float* __restrict__ wc,
        const float* __restrict__ bias, float* __restrict__ hout) {
    int gid = blockIdx.x * 64 + threadIdx.x;
    int d = gid & (D_ - 1), b = gid >> 9;
    float vf = wc[d], vr = wc[D_ + d];
    float bf = bias[d], br = bias[D_ + d];
    const float* u0 = U + d;
    const float* u1 = U + D_ + d;
    const float* u2 = U + 2 * D_ + d;
    const float* xr;  size_t xstride;
    if (xprev) { xr = xprev + d; xstride = D_; }
    else       { xr = U + 3 * (size_t)D_ + d; xstride = (size_t)NU; }
    float* ho = hout + d;
    float c = 0.f;
    #pragma unroll 4
    for (int t = 0; t < T_; ++t) {
        size_t row = (size_t)(t * 16 + b);
        float a0 = u0[row * NU];
        float a1 = u1[row * NU];
        float a2 = u2[row * NU];
        float xv = xr[row * xstride];
        float f = sigm(a1 + vf * c + bf);
        float r = sigm(a2 + vr * c + br);
        c = f * c + (1.f - f) * a0;
        float h = r * c + (1.f - r) * xv;
        ho[row * D_] = h;
    }
}

// ---------------- LSTM recurrence: 16-WG persistent cooperative kernel ------------
// WG wg owns dims [wg*32, wg*32+32). Wave w computes gate w for those dims.
// whh hi/lo slices in VGPRs; h broadcast as bf16 hi/lo packs via global double
// buffer. ALL cross-WG traffic uses RELAXED agent-scope atomics (uncached, served
// at the shared MALL) -> no buffer_wbl2 / buffer_inv per step. Ordering "data
// before flag" is provided by __syncthreads' per-wave s_waitcnt vmcnt(0) drain.
__global__ __launch_bounds__(256, 1) void lstm_rec(const float* __restrict__ gx,
        const unsigned short* __restrict__ Wh, const unsigned short* __restrict__ Wl,
        float* __restrict__ hout,
        unsigned int* __restrict__ hbuf /*2 phases x {hi[4096], lo[4096]}*/,
        unsigned int* __restrict__ cnt) {
    __shared__ __align__(16) unsigned short hH[16][520];
    __shared__ __align__(16) unsigned short hL[16][520];
    __shared__ float G[16][132];
    int tid = threadIdx.x;
    int w = tid >> 6, lane = tid & 63;
    int wg = blockIdx.x;
    int c_ = lane & 15, r_ = lane >> 4;

    s16x8 bh0[16], bh1[16], bl0[16], bl1[16];
    {
        size_t R0 = (size_t)(w * 512 + wg * 32 + c_) * 512;
        size_t R1 = R0 + 16 * 512;
        #pragma unroll
        for (int ks = 0; ks < 16; ++ks) {
            bh0[ks] = *(const s16x8*)(Wh + R0 + ks * 32 + r_ * 8);
            bh1[ks] = *(const s16x8*)(Wh + R1 + ks * 32 + r_ * 8);
            bl0[ks] = *(const s16x8*)(Wl + R0 + ks * 32 + r_ * 8);
            bl1[ks] = *(const s16x8*)(Wl + R1 + ks * 32 + r_ * 8);
        }
    }
    for (int i = tid; i < 16 * 520; i += 256) {
        ((unsigned short*)hH)[i] = 0;
        ((unsigned short*)hL)[i] = 0;
    }
    int eb = tid >> 4;
    int ed = (tid * 2) & 31;
    float cc0 = 0.f, cc1 = 0.f;
    int col0 = w * 512 + wg * 32 + c_;

    // prefetch gx for t=0
    float gxv0[4], gxv1[4];
    {
        const float* gxr = gx;
        #pragma unroll
        for (int r = 0; r < 4; ++r) {
            int bt = r_ * 4 + r;
            gxv0[r] = gxr[(size_t)bt * 2048 + col0];
            gxv1[r] = gxr[(size_t)bt * 2048 + col0 + 16];
        }
    }
    __syncthreads();

    for (int t = 0; t < T_; ++t) {
        f32x4 acc0 = {0.f, 0.f, 0.f, 0.f};
        f32x4 acc1 = {0.f, 0.f, 0.f, 0.f};
        #pragma unroll
        for (int ks = 0; ks < 16; ++ks) {
            s16x8 ah = *(const s16x8*)&hH[c_][ks * 32 + r_ * 8];
            s16x8 al = *(const s16x8*)&hL[c_][ks * 32 + r_ * 8];
            acc0 = __builtin_amdgcn_mfma_f32_16x16x32_bf16(ah, bh0[ks], acc0, 0, 0, 0);
            acc1 = __builtin_amdgcn_mfma_f32_16x16x32_bf16(ah, bh1[ks], acc1, 0, 0, 0);
            acc0 = __builtin_amdgcn_mfma_f32_16x16x32_bf16(al, bh0[ks], acc0, 0, 0, 0);
            acc1 = __builtin_amdgcn_mfma_f32_16x16x32_bf16(al, bh1[ks], acc1, 0, 0, 0);
            acc0 = __builtin_amdgcn_mfma_f32_16x16x32_bf16(ah, bl0[ks], acc0, 0, 0, 0);
            acc1 = __builtin_amdgcn_mfma_f32_16x16x32_bf16(ah, bl1[ks], acc1, 0, 0, 0);
        }
        #pragma unroll
        for (int r = 0; r < 4; ++r) {
            int bt = r_ * 4 + r;
            G[bt][w * 32 + c_]      = acc0[r] + gxv0[r];
            G[bt][w * 32 + 16 + c_] = acc1[r] + gxv1[r];
        }
        __syncthreads();
        float iv0 = G[eb][ed],     fv0 = G[eb][32 + ed], gv0 = G[eb][64 + ed], ov0 = G[eb][96 + ed];
        float iv1 = G[eb][ed + 1], fv1 = G[eb][33 + ed], gv1 = G[eb][65 + ed], ov1 = G[eb][97 + ed];
        cc0 = sigm(fv0) * cc0 + sigm(iv0) * tanhf(gv0);
        cc1 = sigm(fv1) * cc1 + sigm(iv1) * tanhf(gv1);
        float h0 = sigm(ov0) * tanhf(cc0);
        float h1 = sigm(ov1) * tanhf(cc1);
        size_t orow = (size_t)(t * 16 + eb) * D_ + wg * 32 + ed;
        hout[orow] = h0; hout[orow + 1] = h1;
        unsigned short h0h, h0l, h1h, h1l;
        split2(h0, h0h, h0l); split2(h1, h1h, h1l);
        unsigned packH = (unsigned)h0h | ((unsigned)h1h << 16);
        unsigned packL = (unsigned)h0l | ((unsigned)h1l << 16);
        int bufs = ((t + 1) & 1) * 8192;
        int hidx = (eb * 512 + wg * 32 + ed) >> 1;
        __hip_atomic_store(&hbuf[bufs + hidx], packH, __ATOMIC_RELAXED, __HIP_MEMORY_SCOPE_AGENT);
        __hip_atomic_store(&hbuf[bufs + 4096 + hidx], packL, __ATOMIC_RELAXED, __HIP_MEMORY_SCOPE_AGENT);
        __syncthreads();   // each wave drains vmcnt(0) before s_barrier -> hbuf stores at MALL
        if (tid == 0) {
            __hip_atomic_fetch_add(cnt, 1u, __ATOMIC_RELAXED, __HIP_MEMORY_SCOPE_AGENT);
        }
        // prefetch gx for t+1 while waiting (independent of the barrier)
        if (t + 1 < T_) {
            const float* gxr = gx + (size_t)((t + 1) * 16) * 2048;
            #pragma unroll
            for (int r = 0; r < 4; ++r) {
                int bt = r_ * 4 + r;
                gxv0[r] = gxr[(size_t)bt * 2048 + col0];
                gxv1[r] = gxr[(size_t)bt * 2048 + col0 + 16];
            }
        }
        if (tid == 0) {
            unsigned target = 16u * (unsigned)(t + 1);
            while (__hip_atomic_load(cnt, __ATOMIC_RELAXED, __HIP_MEMORY_SCOPE_AGENT) < target) {
                __builtin_amdgcn_s_sleep(2);
            }
        }
        __syncthreads();
        #pragma unroll
        for (int i = 0; i < 16; ++i) {
            int idx = i * 256 + tid;
            unsigned uh = __hip_atomic_load(&hbuf[bufs + idx], __ATOMIC_RELAXED, __HIP_MEMORY_SCOPE_AGENT);
            unsigned ul = __hip_atomic_load(&hbuf[bufs + 4096 + idx], __ATOMIC_RELAXED, __HIP_MEMORY_SCOPE_AGENT);
            int bb = idx >> 8;
            int kk = (idx & 255) * 2;
            *(unsigned*)&hH[bb][kk] = uh;
            *(unsigned*)&hL[bb][kk] = ul;
        }
        __syncthreads();
    }
}

// ---------------- classifier: out[b][t][v] = LN(h)[row] . cls_w[:,v] (fp32) ------
__global__ __launch_bounds__(256) void cls_gemm(const float* __restrict__ xn,
        const float* __restrict__ wcls, float* __restrict__ out) {
    __shared__ float wl[512][32];
    int tid = threadIdx.x;
    for (int idx = tid; idx < 512 * VO; idx += 256) {
        int k = idx / VO, v = idx - k * VO;
        wl[k][v] = wcls[idx];
    }
    __syncthreads();
    int r8 = tid >> 5, v = tid & 31;
    int row = blockIdx.x * 8 + r8;
    if (v >= VO) return;
    const float* xr = xn + (size_t)row * D_;
    float acc = 0.f;
    #pragma unroll 8
    for (int k = 0; k < 512; ++k) acc += xr[k] * wl[k][v];
    int b = row & 15, t = row >> 4;
    out[((size_t)b * T_ + t) * VO + v] = acc;
}

// ------------------------------- launch ------------------------------------------
// Workspace layout (~214 MB):
//   U  : M*1536 fp32   -- SRU-layer GEMM out; [U|hP] = 2048-wide gx
//   hP : M*512 fp32    -- contiguous after U (gx tail)
//   hQ : M*512 fp32
//   xnh/xnl : M*512 bf16 planes; per-layer reused weight buffers; hbuf; cnts
extern "C" void kernel_launch(void* const* d_in, const int* in_sizes, int n_in,
                              void* d_out, int out_size, void* d_ws, size_t ws_size,
                              hipStream_t stream) {
    const float* x        = (const float*)d_in[0];
    const float* sru_w0   = (const float*)d_in[1];
    const float* sru_wc0  = (const float*)d_in[2];
    const float* sru_b0   = (const float*)d_in[3];
    const float* sru_ln0g = (const float*)d_in[4];
    const float* sru_ln0b = (const float*)d_in[5];
    const float* sru_w    = (const float*)d_in[6];
    const float* sru_wc   = (const float*)d_in[7];
    const float* sru_b    = (const float*)d_in[8];
    const float* sru_lng  = (const float*)d_in[9];
    const float* sru_lnb  = (const float*)d_in[10];
    const float* lstm_lng = (const float*)d_in[11];
    const float* lstm_lnb = (const float*)d_in[12];
    const float* lstm_wih = (const float*)d_in[13];
    const float* lstm_whh = (const float*)d_in[14];
    const float* lstm_bih = (const float*)d_in[15];
    const float* lstm_bhh = (const float*)d_in[16];
    const float* cls_lng  = (const float*)d_in[17];
    const float* cls_lnb  = (const float*)d_in[18];
    const float* cls_w    = (const float*)d_in[19];
    float* out = (float*)d_out;

    char* ws = (char*)d_ws;
    size_t off = 0;
    auto alloc = [&](size_t bytes) -> void* {
        off = (off + 255) & ~(size_t)255;
        void* p = ws + off;
        off += bytes;
        return p;
    };
    float* U             = (float*)alloc((size_t)M_ * 1536 * 4);
    float* hP            = (float*)alloc((size_t)M_ * D_ * 4);     // contiguous after U
    float* hQ            = (float*)alloc((size_t)M_ * D_ * 4);
    unsigned short* xnh  = (unsigned short*)alloc((size_t)M_ * D_ * 2);
    unsigned short* xnl  = (unsigned short*)alloc((size_t)M_ * D_ * 2);
    unsigned short* w0h  = (unsigned short*)alloc((size_t)2048 * 96 * 2);
    unsigned short* w0l  = (unsigned short*)alloc((size_t)2048 * 96 * 2);
    unsigned short* swh  = (unsigned short*)alloc((size_t)1536 * 512 * 2);  // per-layer reuse
    unsigned short* swl  = (unsigned short*)alloc((size_t)1536 * 512 * 2);
    unsigned short* wihh = (unsigned short*)alloc((size_t)2048 * 512 * 2);  // per-layer reuse
    unsigned short* wihl = (unsigned short*)alloc((size_t)2048 * 512 * 2);
    unsigned short* whhh = (unsigned short*)alloc((size_t)2048 * 512 * 2);  // per-layer reuse
    unsigned short* whhl = (unsigned short*)alloc((size_t)2048 * 512 * 2);
    unsigned int* hbuf   = (unsigned int*)alloc((size_t)2 * 2 * 4096 * 4);
    unsigned int* cnts   = (unsigned int*)alloc(8 * 4);
    float* gx = U;   // 2048-wide outputs span [U | hP] contiguously

    hipLaunchKernelGGL(zero_cnt, dim3(1), dim3(64), 0, stream, cnts);
    hipLaunchKernelGGL(conv_w0, dim3(768), dim3(256), 0, stream, sru_w0, w0h, w0l);

    // ---- SRU layer 0 (gx = [U|hP], output -> hQ) ----
    hipLaunchKernelGGL(ln80_kernel, dim3(4096), dim3(256), 0, stream, x, sru_ln0g, sru_ln0b, xnh, xnl);
    hipLaunchKernelGGL(gemm_split, dim3(2048 / 64, M_ / 64), dim3(256), 0, stream,
                       xnh, xnl, w0h, w0l, gx, 2048, 96, (const float*)nullptr, (const float*)nullptr);
    hipLaunchKernelGGL(sru_rec, dim3(128), dim3(64), 0, stream,
                       gx, 2048, (const float*)nullptr, sru_wc0, sru_b0, hQ);

    float* hcur = hQ; float* hnxt = hP;
    // ---- SRU layers 1..7 (GEMM writes U only; h ping-pongs hQ<->hP) ----
    for (int l = 0; l < 7; ++l) {
        hipLaunchKernelGGL(conv_sruw1, dim3(3072), dim3(256), 0, stream,
                           sru_w + (size_t)l * 512 * 1536, swh, swl);
        hipLaunchKernelGGL(ln512_bf16, dim3(4096), dim3(256), 0, stream,
                           hcur, sru_lng + (size_t)l * 512, sru_lnb + (size_t)l * 512, xnh, xnl);
        hipLaunchKernelGGL(gemm_split, dim3(1536 / 64, M_ / 64), dim3(256), 0, stream,
                           xnh, xnl, swh, swl, U, 1536, 512,
                           (const float*)nullptr, (const float*)nullptr);
        hipLaunchKernelGGL(sru_rec, dim3(128), dim3(64), 0, stream,
                           U, 1536, hcur, sru_wc + (size_t)l * 1024, sru_b + (size_t)l * 1024, hnxt);
        float* tmp = hcur; hcur = hnxt; hnxt = tmp;
    }
    // after 7 layers: hcur == hP

    // ---- LSTM layers 0..2 (gx = [U|hP]; hP dead after its LN; out -> hQ in-place) ----
    for (int l = 0; l < 3; ++l) {
        hipLaunchKernelGGL(conv_split, dim3(4096), dim3(256), 0, stream,
                           lstm_wih + (size_t)l * 2048 * 512, wihh, wihl, 2048 * 512);
        hipLaunchKernelGGL(conv_split, dim3(4096), dim3(256), 0, stream,
                           lstm_whh + (size_t)l * 2048 * 512, whhh, whhl, 2048 * 512);
        hipLaunchKernelGGL(ln512_bf16, dim3(4096), dim3(256), 0, stream,
                           hcur, lstm_lng + (size_t)l * 512, lstm_lnb + (size_t)l * 512, xnh, xnl);
        hipLaunchKernelGGL(gemm_split, dim3(2048 / 64, M_ / 64), dim3(256), 0, stream,
                           xnh, xnl, wihh, wihl, gx, 2048, 512,
                           lstm_bih + (size_t)l * 2048, lstm_bhh + (size_t)l * 2048);
        hipLaunchKernelGGL(lstm_rec, dim3(16), dim3(256), 0, stream,
                           gx, whhh, whhl, hQ, hbuf, cnts + l);
        hcur = hQ;
    }
    // ---- classifier ----
    hipLaunchKernelGGL(ln512_f32, dim3(4096), dim3(256), 0, stream, hcur, cls_lng, cls_lnb, (float*)U);
    hipLaunchKernelGGL(cls_gemm, dim3(2048), dim3(256), 0, stream, (const float*)U, cls_w, out);
}

// Round 5
// 22211.449 us; speedup vs baseline: 1.4808x; 1.1376x over previous
//
#include <hip/hip_runtime.h>
#include <stdint.h>
#include <stddef.h>

#define B_ 16
#define T_ 1024
#define F_ 80
#define D_ 512
#define M_ 16384   // T*B rows, row index = t*16 + b
#define VO 29      // V+1

typedef float f32x4 __attribute__((ext_vector_type(4)));
typedef short s16x8 __attribute__((ext_vector_type(8)));
typedef unsigned short u16x8 __attribute__((ext_vector_type(8)));

static __device__ __forceinline__ unsigned short f2bf(float f) {
    union { float f; unsigned u; } v; v.f = f;
    unsigned r = v.u + 0x7FFFu + ((v.u >> 16) & 1u);
    return (unsigned short)(r >> 16);
}
static __device__ __forceinline__ float bf2f(unsigned short h) {
    union { unsigned u; float f; } v; v.u = ((unsigned)h) << 16; return v.f;
}
static __device__ __forceinline__ void split2(float v, unsigned short& hi, unsigned short& lo) {
    hi = f2bf(v);
    lo = f2bf(v - bf2f(hi));
}
static __device__ __forceinline__ float sigm(float x) {
    return 1.0f / (1.0f + __expf(-x));
}
static __device__ __forceinline__ float fast_tanh(float x) {
    return 1.0f - 2.0f / (__expf(2.0f * x) + 1.0f);
}
static __device__ __forceinline__ float wred(float v) {
    #pragma unroll
    for (int off = 1; off < 64; off <<= 1) v += __shfl_xor(v, off, 64);
    return v;
}

// ---------------- weight conversion (fp32 -> bf16 hi/lo split) ----------------
__global__ __launch_bounds__(256) void conv_w0(const float* __restrict__ W,
        unsigned short* __restrict__ Bh, unsigned short* __restrict__ Bl) {
    int gid = blockIdx.x * 256 + threadIdx.x;     // 2048*96
    int n = gid / 96, k = gid - n * 96;
    float v = (k < 80) ? W[(size_t)k * 2048 + n] : 0.0f;
    unsigned short h, l; split2(v, h, l);
    Bh[gid] = h; Bl[gid] = l;
}
__global__ __launch_bounds__(256) void conv_sruw1(const float* __restrict__ W,
        unsigned short* __restrict__ Bh, unsigned short* __restrict__ Bl) {
    int gid = blockIdx.x * 256 + threadIdx.x;     // 1536*512
    int n = gid >> 9, k = gid & 511;
    float v = W[(size_t)k * 1536 + n];
    unsigned short h, lo; split2(v, h, lo);
    Bh[gid] = h; Bl[gid] = lo;
}
__global__ __launch_bounds__(256) void conv_split(const float* __restrict__ W,
        unsigned short* __restrict__ Oh, unsigned short* __restrict__ Ol, int n) {
    int gid = blockIdx.x * 256 + threadIdx.x;
    if (gid < n) {
        unsigned short h, l; split2(W[gid], h, l);
        Oh[gid] = h; Ol[gid] = l;
    }
}
__global__ void zero_flags(unsigned int* c) { c[threadIdx.x] = 0u; }  // 256 thr

// ---------------- LayerNorm kernels ----------------
__global__ __launch_bounds__(256) void ln80_kernel(const float* __restrict__ x,
        const float* __restrict__ g, const float* __restrict__ bta,
        unsigned short* __restrict__ xh, unsigned short* __restrict__ xl) {
    int w = threadIdx.x >> 6, lane = threadIdx.x & 63;
    int row = blockIdx.x * 4 + w;          // row = t*16 + b
    int b = row & 15, t = row >> 4;
    const float* xr = x + ((size_t)b * T_ + t) * F_;
    float v0 = xr[lane];
    float v1 = (lane < 16) ? xr[64 + lane] : 0.0f;
    float mean = wred(v0 + v1) * (1.0f / 80.0f);
    float d0 = v0 - mean;
    float d1 = (lane < 16) ? (v1 - mean) : 0.0f;
    float var = wred(d0 * d0 + d1 * d1) * (1.0f / 80.0f);
    float rstd = rsqrtf(var + 1e-5f);
    float o0 = d0 * rstd * g[lane] + bta[lane];
    unsigned short h, l; split2(o0, h, l);
    xh[(size_t)row * 96 + lane] = h;
    xl[(size_t)row * 96 + lane] = l;
    if (lane < 32) {
        unsigned short hv = 0, lv = 0;
        if (lane < 16) {
            float o1 = d1 * rstd * g[64 + lane] + bta[64 + lane];
            split2(o1, hv, lv);
        }
        xh[(size_t)row * 96 + 64 + lane] = hv;
        xl[(size_t)row * 96 + 64 + lane] = lv;
    }
}

__global__ __launch_bounds__(256) void ln512_bf16(const float* __restrict__ hsrc,
        const float* __restrict__ g, const float* __restrict__ bta,
        unsigned short* __restrict__ oh, unsigned short* __restrict__ ol) {
    int w = threadIdx.x >> 6, lane = threadIdx.x & 63;
    size_t row = (size_t)blockIdx.x * 4 + w;
    const float* hr = hsrc + row * D_;
    float4 p0 = *(const float4*)(hr + lane * 8);
    float4 p1 = *(const float4*)(hr + lane * 8 + 4);
    float s = p0.x + p0.y + p0.z + p0.w + p1.x + p1.y + p1.z + p1.w;
    float mean = wred(s) * (1.0f / 512.0f);
    float d[8] = {p0.x - mean, p0.y - mean, p0.z - mean, p0.w - mean,
                  p1.x - mean, p1.y - mean, p1.z - mean, p1.w - mean};
    float q = 0.f;
    #pragma unroll
    for (int i = 0; i < 8; ++i) q += d[i] * d[i];
    float rstd = rsqrtf(wred(q) * (1.0f / 512.0f) + 1e-5f);
    const float* gp = g + lane * 8;
    const float* bp = bta + lane * 8;
    u16x8 vh, vl;
    #pragma unroll
    for (int i = 0; i < 8; ++i) {
        float o = d[i] * rstd * gp[i] + bp[i];
        unsigned short hh, ll; split2(o, hh, ll);
        vh[i] = hh; vl[i] = ll;
    }
    *(u16x8*)(oh + row * D_ + lane * 8) = vh;
    *(u16x8*)(ol + row * D_ + lane * 8) = vl;
}

__global__ __launch_bounds__(256) void ln512_f32(const float* __restrict__ hsrc,
        const float* __restrict__ g, const float* __restrict__ bta,
        float* __restrict__ o) {
    int w = threadIdx.x >> 6, lane = threadIdx.x & 63;
    size_t row = (size_t)blockIdx.x * 4 + w;
    const float* hr = hsrc + row * D_;
    float4 p0 = *(const float4*)(hr + lane * 8);
    float4 p1 = *(const float4*)(hr + lane * 8 + 4);
    float s = p0.x + p0.y + p0.z + p0.w + p1.x + p1.y + p1.z + p1.w;
    float mean = wred(s) * (1.0f / 512.0f);
    float d[8] = {p0.x - mean, p0.y - mean, p0.z - mean, p0.w - mean,
                  p1.x - mean, p1.y - mean, p1.z - mean, p1.w - mean};
    float q = 0.f;
    #pragma unroll
    for (int i = 0; i < 8; ++i) q += d[i] * d[i];
    float rstd = rsqrtf(wred(q) * (1.0f / 512.0f) + 1e-5f);
    const float* gp = g + lane * 8;
    const float* bp = bta + lane * 8;
    float* op = o + row * D_ + lane * 8;
    #pragma unroll
    for (int i = 0; i < 8; ++i) op[i] = d[i] * rstd * gp[i] + bp[i];
}

// ------- split bf16 MFMA GEMM (fp32-accurate): C = A * Bt^T (+bias0+bias1) -------
__global__ __launch_bounds__(256) void gemm_split(
        const unsigned short* __restrict__ Ah, const unsigned short* __restrict__ Al,
        const unsigned short* __restrict__ Bh, const unsigned short* __restrict__ Bl,
        float* __restrict__ C, int N, int Kp,
        const float* __restrict__ bias0, const float* __restrict__ bias1) {
    __shared__ __align__(16) unsigned short sAh[64][40];
    __shared__ __align__(16) unsigned short sAl[64][40];
    __shared__ __align__(16) unsigned short sBh[64][40];
    __shared__ __align__(16) unsigned short sBl[64][40];
    int tid = threadIdx.x;
    int w = tid >> 6, lane = tid & 63;
    int r_ = lane >> 4, c_ = lane & 15;
    int mBase = blockIdx.y * 64, nBase = blockIdx.x * 64;
    int srow = tid >> 2, sseg = (tid & 3) * 8;
    const unsigned short* gAh = Ah + (size_t)(mBase + srow) * Kp + sseg;
    const unsigned short* gAl = Al + (size_t)(mBase + srow) * Kp + sseg;
    const unsigned short* gBh = Bh + (size_t)(nBase + srow) * Kp + sseg;
    const unsigned short* gBl = Bl + (size_t)(nBase + srow) * Kp + sseg;
    f32x4 acc[4] = {{0.f,0.f,0.f,0.f},{0.f,0.f,0.f,0.f},{0.f,0.f,0.f,0.f},{0.f,0.f,0.f,0.f}};
    for (int kt = 0; kt < Kp; kt += 32) {
        *(u16x8*)&sAh[srow][sseg] = *(const u16x8*)(gAh + kt);
        *(u16x8*)&sAl[srow][sseg] = *(const u16x8*)(gAl + kt);
        *(u16x8*)&sBh[srow][sseg] = *(const u16x8*)(gBh + kt);
        *(u16x8*)&sBl[srow][sseg] = *(const u16x8*)(gBl + kt);
        __syncthreads();
        s16x8 ah = *(const s16x8*)&sAh[w * 16 + c_][r_ * 8];
        s16x8 al = *(const s16x8*)&sAl[w * 16 + c_][r_ * 8];
        #pragma unroll
        for (int nt = 0; nt < 4; ++nt) {
            s16x8 bh = *(const s16x8*)&sBh[nt * 16 + c_][r_ * 8];
            s16x8 bl = *(const s16x8*)&sBl[nt * 16 + c_][r_ * 8];
            acc[nt] = __builtin_amdgcn_mfma_f32_16x16x32_bf16(ah, bh, acc[nt], 0, 0, 0);
            acc[nt] = __builtin_amdgcn_mfma_f32_16x16x32_bf16(al, bh, acc[nt], 0, 0, 0);
            acc[nt] = __builtin_amdgcn_mfma_f32_16x16x32_bf16(ah, bl, acc[nt], 0, 0, 0);
        }
        __syncthreads();
    }
    #pragma unroll
    for (int r = 0; r < 4; ++r) {
        int m = mBase + w * 16 + r_ * 4 + r;
        float* crow = C + (size_t)m * N + nBase;
        #pragma unroll
        for (int nt = 0; nt < 4; ++nt) {
            int n = nBase + nt * 16 + c_;
            float bb = 0.f;
            if (bias0) bb += bias0[n];
            if (bias1) bb += bias1[n];
            crow[nt * 16 + c_] = acc[nt][r] + bb;
        }
    }
}

// ---------------- SRU recurrence: 8192 independent (b,d) chains ----------------
__global__ __launch_bounds__(64) void sru_rec(const float* __restrict__ U, int NU,
        const float* __restrict__ xprev, const float* __restrict__ wc,
        const float* __restrict__ bias, float* __restrict__ hout) {
    int gid = blockIdx.x * 64 + threadIdx.x;
    int d = gid & (D_ - 1), b = gid >> 9;
    float vf = wc[d], vr = wc[D_ + d];
    float bf = bias[d], br = bias[D_ + d];
    const float* u0 = U + d;
    const float* u1 = U + D_ + d;
    const float* u2 = U + 2 * D_ + d;
    const float* xr;  size_t xstride;
    if (xprev) { xr = xprev + d; xstride = D_; }
    else       { xr = U + 3 * (size_t)D_ + d; xstride = (size_t)NU; }
    float* ho = hout + d;
    float c = 0.f;
    #pragma unroll 4
    for (int t = 0; t < T_; ++t) {
        size_t row = (size_t)(t * 16 + b);
        float a0 = u0[row * NU];
        float a1 = u1[row * NU];
        float a2 = u2[row * NU];
        float xv = xr[row * xstride];
        float f = sigm(a1 + vf * c + bf);
        float r = sigm(a2 + vr * c + br);
        c = f * c + (1.f - f) * a0;
        float h = r * c + (1.f - r) * xv;
        ho[row * D_] = h;
    }
}

// ---------------- LSTM recurrence: 16-WG persistent cooperative kernel ------------
// Per-wave flag barrier, relaxed agent-scope traffic only (MALL-served, no L2
// writeback/invalidate). Per step: 2 __syncthreads, per-wave vmcnt drain + flag
// store, 64-lane coalesced flag poll, u64-wide h reload.
__global__ __launch_bounds__(256, 1) void lstm_rec(const float* __restrict__ gx,
        const unsigned short* __restrict__ Wh, const unsigned short* __restrict__ Wl,
        float* __restrict__ hout,
        unsigned int* __restrict__ hbuf /*2 phases x {hi[4096], lo[4096]}*/,
        unsigned int* __restrict__ flags /*64, zeroed*/) {
    __shared__ __align__(16) unsigned short hH[16][520];
    __shared__ __align__(16) unsigned short hL[16][520];
    __shared__ float G[16][132];
    const int tid = threadIdx.x;
    const int w = tid >> 6, lane = tid & 63;
    const int wg = blockIdx.x;
    const int c_ = lane & 15, r_ = lane >> 4;
    const int wv = wg * 4 + w;

    s16x8 bh0[16], bh1[16], bl0[16], bl1[16];
    {
        size_t R0 = (size_t)(w * 512 + wg * 32 + c_) * 512;
        size_t R1 = R0 + 16 * 512;
        #pragma unroll
        for (int ks = 0; ks < 16; ++ks) {
            bh0[ks] = *(const s16x8*)(Wh + R0 + ks * 32 + r_ * 8);
            bh1[ks] = *(const s16x8*)(Wh + R1 + ks * 32 + r_ * 8);
            bl0[ks] = *(const s16x8*)(Wl + R0 + ks * 32 + r_ * 8);
            bl1[ks] = *(const s16x8*)(Wl + R1 + ks * 32 + r_ * 8);
        }
    }
    for (int i = tid; i < 16 * 520; i += 256) {
        ((unsigned short*)hH)[i] = 0;
        ((unsigned short*)hL)[i] = 0;
    }
    const int eb = tid >> 4;
    const int ed = (tid * 2) & 31;
    float cc0 = 0.f, cc1 = 0.f;
    const int col0 = w * 512 + wg * 32 + c_;

    float gxv0[4], gxv1[4];
    {
        const float* gxr = gx;
        #pragma unroll
        for (int r = 0; r < 4; ++r) {
            int bt = r_ * 4 + r;
            gxv0[r] = gxr[(size_t)bt * 2048 + col0];
            gxv1[r] = gxr[(size_t)bt * 2048 + col0 + 16];
        }
    }
    __syncthreads();

    for (int t = 0; t < T_; ++t) {
        // ---- MFMA: gate slice = h @ whh_slice^T (3-term split) ----
        f32x4 acc0 = {0.f, 0.f, 0.f, 0.f};
        f32x4 acc1 = {0.f, 0.f, 0.f, 0.f};
        #pragma unroll
        for (int ks = 0; ks < 16; ++ks) {
            s16x8 ah = *(const s16x8*)&hH[c_][ks * 32 + r_ * 8];
            s16x8 al = *(const s16x8*)&hL[c_][ks * 32 + r_ * 8];
            acc0 = __builtin_amdgcn_mfma_f32_16x16x32_bf16(ah, bh0[ks], acc0, 0, 0, 0);
            acc1 = __builtin_amdgcn_mfma_f32_16x16x32_bf16(ah, bh1[ks], acc1, 0, 0, 0);
            acc0 = __builtin_amdgcn_mfma_f32_16x16x32_bf16(al, bh0[ks], acc0, 0, 0, 0);
            acc1 = __builtin_amdgcn_mfma_f32_16x16x32_bf16(al, bh1[ks], acc1, 0, 0, 0);
            acc0 = __builtin_amdgcn_mfma_f32_16x16x32_bf16(ah, bl0[ks], acc0, 0, 0, 0);
            acc1 = __builtin_amdgcn_mfma_f32_16x16x32_bf16(ah, bl1[ks], acc1, 0, 0, 0);
        }
        #pragma unroll
        for (int r = 0; r < 4; ++r) {
            int bt = r_ * 4 + r;
            G[bt][w * 32 + c_]      = acc0[r] + gxv0[r];
            G[bt][w * 32 + 16 + c_] = acc1[r] + gxv1[r];
        }
        __syncthreads();                                   // sync1: G ready, hH free
        // ---- elementwise LSTM cell (2 dims/thread) ----
        float iv0 = G[eb][ed],     fv0 = G[eb][32 + ed], gv0 = G[eb][64 + ed], ov0 = G[eb][96 + ed];
        float iv1 = G[eb][ed + 1], fv1 = G[eb][33 + ed], gv1 = G[eb][65 + ed], ov1 = G[eb][97 + ed];
        cc0 = sigm(fv0) * cc0 + sigm(iv0) * fast_tanh(gv0);
        cc1 = sigm(fv1) * cc1 + sigm(iv1) * fast_tanh(gv1);
        float h0 = sigm(ov0) * fast_tanh(cc0);
        float h1 = sigm(ov1) * fast_tanh(cc1);
        size_t orow = (size_t)(t * 16 + eb) * D_ + wg * 32 + ed;
        hout[orow] = h0; hout[orow + 1] = h1;
        unsigned short h0h, h0l, h1h, h1l;
        split2(h0, h0h, h0l); split2(h1, h1h, h1l);
        unsigned packH = (unsigned)h0h | ((unsigned)h1h << 16);
        unsigned packL = (unsigned)h0l | ((unsigned)h1l << 16);
        const int bufs = ((t + 1) & 1) * 8192;
        int hidx = (eb * 512 + wg * 32 + ed) >> 1;
        __hip_atomic_store(&hbuf[bufs + hidx], packH, __ATOMIC_RELAXED, __HIP_MEMORY_SCOPE_AGENT);
        __hip_atomic_store(&hbuf[bufs + 4096 + hidx], packL, __ATOMIC_RELAXED, __HIP_MEMORY_SCOPE_AGENT);
        // per-wave drain: our hbuf/hout stores acked at coherence point, then flag
        asm volatile("s_waitcnt vmcnt(0)" ::: "memory");
        if (lane == 0)
            __hip_atomic_store(&flags[wv], (unsigned)(t + 1), __ATOMIC_RELAXED, __HIP_MEMORY_SCOPE_AGENT);
        // prefetch gx for t+1 while the barrier resolves
        if (t + 1 < T_) {
            const float* gxr = gx + (size_t)((t + 1) * 16) * 2048;
            #pragma unroll
            for (int r = 0; r < 4; ++r) {
                int bt = r_ * 4 + r;
                gxv0[r] = gxr[(size_t)bt * 2048 + col0];
                gxv1[r] = gxr[(size_t)bt * 2048 + col0 + 16];
            }
        }
        // ---- per-wave poll: all 64 wave-flags >= t+1 ----
        {
            const unsigned tgt = (unsigned)(t + 1);
            while (true) {
                unsigned f = __hip_atomic_load(&flags[lane], __ATOMIC_RELAXED, __HIP_MEMORY_SCOPE_AGENT);
                if (__all(f >= tgt)) break;
                __builtin_amdgcn_s_sleep(1);
            }
        }
        // ---- reload h into LDS (u64-wide, coalesced) ----
        #pragma unroll
        for (int j = 0; j < 8; ++j) {
            int q = j * 512 + tid * 2;      // dword index in plane
            unsigned long long uh = __hip_atomic_load(
                (const unsigned long long*)&hbuf[bufs + q], __ATOMIC_RELAXED, __HIP_MEMORY_SCOPE_AGENT);
            unsigned long long ul = __hip_atomic_load(
                (const unsigned long long*)&hbuf[bufs + 4096 + q], __ATOMIC_RELAXED, __HIP_MEMORY_SCOPE_AGENT);
            int bb = q >> 8;
            int dd = (q & 255) * 2;
            *(unsigned long long*)&hH[bb][dd] = uh;
            *(unsigned long long*)&hL[bb][dd] = ul;
        }
        __syncthreads();                                   // sync2: hH/hL published
    }
}

// ---------------- classifier ----------------
__global__ __launch_bounds__(256) void cls_gemm(const float* __restrict__ xn,
        const float* __restrict__ wcls, float* __restrict__ out) {
    __shared__ float wl[512][32];
    int tid = threadIdx.x;
    for (int idx = tid; idx < 512 * VO; idx += 256) {
        int k = idx / VO, v = idx - k * VO;
        wl[k][v] = wcls[idx];
    }
    __syncthreads();
    int r8 = tid >> 5, v = tid & 31;
    int row = blockIdx.x * 8 + r8;
    if (v >= VO) return;
    const float* xr = xn + (size_t)row * D_;
    float acc = 0.f;
    #pragma unroll 8
    for (int k = 0; k < 512; ++k) acc += xr[k] * wl[k][v];
    int b = row & 15, t = row >> 4;
    out[((size_t)b * T_ + t) * VO + v] = acc;
}

// ------------------------------- launch ------------------------------------------
extern "C" void kernel_launch(void* const* d_in, const int* in_sizes, int n_in,
                              void* d_out, int out_size, void* d_ws, size_t ws_size,
                              hipStream_t stream) {
    const float* x        = (const float*)d_in[0];
    const float* sru_w0   = (const float*)d_in[1];
    const float* sru_wc0  = (const float*)d_in[2];
    const float* sru_b0   = (const float*)d_in[3];
    const float* sru_ln0g = (const float*)d_in[4];
    const float* sru_ln0b = (const float*)d_in[5];
    const float* sru_w    = (const float*)d_in[6];
    const float* sru_wc   = (const float*)d_in[7];
    const float* sru_b    = (const float*)d_in[8];
    const float* sru_lng  = (const float*)d_in[9];
    const float* sru_lnb  = (const float*)d_in[10];
    const float* lstm_lng = (const float*)d_in[11];
    const float* lstm_lnb = (const float*)d_in[12];
    const float* lstm_wih = (const float*)d_in[13];
    const float* lstm_whh = (const float*)d_in[14];
    const float* lstm_bih = (const float*)d_in[15];
    const float* lstm_bhh = (const float*)d_in[16];
    const float* cls_lng  = (const float*)d_in[17];
    const float* cls_lnb  = (const float*)d_in[18];
    const float* cls_w    = (const float*)d_in[19];
    float* out = (float*)d_out;

    char* ws = (char*)d_ws;
    size_t off = 0;
    auto alloc = [&](size_t bytes) -> void* {
        off = (off + 255) & ~(size_t)255;
        void* p = ws + off;
        off += bytes;
        return p;
    };
    float* U             = (float*)alloc((size_t)M_ * 1536 * 4);
    float* hP            = (float*)alloc((size_t)M_ * D_ * 4);     // contiguous after U
    float* hQ            = (float*)alloc((size_t)M_ * D_ * 4);
    unsigned short* xnh  = (unsigned short*)alloc((size_t)M_ * D_ * 2);
    unsigned short* xnl  = (unsigned short*)alloc((size_t)M_ * D_ * 2);
    unsigned short* w0h  = (unsigned short*)alloc((size_t)2048 * 96 * 2);
    unsigned short* w0l  = (unsigned short*)alloc((size_t)2048 * 96 * 2);
    unsigned short* swh  = (unsigned short*)alloc((size_t)1536 * 512 * 2);  // per-layer reuse
    unsigned short* swl  = (unsigned short*)alloc((size_t)1536 * 512 * 2);
    unsigned short* wihh = (unsigned short*)alloc((size_t)2048 * 512 * 2);  // per-layer reuse
    unsigned short* wihl = (unsigned short*)alloc((size_t)2048 * 512 * 2);
    unsigned short* whhh = (unsigned short*)alloc((size_t)2048 * 512 * 2);  // per-layer reuse
    unsigned short* whhl = (unsigned short*)alloc((size_t)2048 * 512 * 2);
    unsigned int* hbuf   = (unsigned int*)alloc((size_t)2 * 2 * 4096 * 4);
    unsigned int* flags  = (unsigned int*)alloc(256 * 4);
    float* gx = U;   // 2048-wide outputs span [U | hP] contiguously

    hipLaunchKernelGGL(zero_flags, dim3(1), dim3(256), 0, stream, flags);
    hipLaunchKernelGGL(conv_w0, dim3(768), dim3(256), 0, stream, sru_w0, w0h, w0l);

    // ---- SRU layer 0 (gx = [U|hP], output -> hQ) ----
    hipLaunchKernelGGL(ln80_kernel, dim3(4096), dim3(256), 0, stream, x, sru_ln0g, sru_ln0b, xnh, xnl);
    hipLaunchKernelGGL(gemm_split, dim3(2048 / 64, M_ / 64), dim3(256), 0, stream,
                       xnh, xnl, w0h, w0l, gx, 2048, 96, (const float*)nullptr, (const float*)nullptr);
    hipLaunchKernelGGL(sru_rec, dim3(128), dim3(64), 0, stream,
                       gx, 2048, (const float*)nullptr, sru_wc0, sru_b0, hQ);

    float* hcur = hQ; float* hnxt = hP;
    // ---- SRU layers 1..7 (GEMM writes U only; h ping-pongs hQ<->hP) ----
    for (int l = 0; l < 7; ++l) {
        hipLaunchKernelGGL(conv_sruw1, dim3(3072), dim3(256), 0, stream,
                           sru_w + (size_t)l * 512 * 1536, swh, swl);
        hipLaunchKernelGGL(ln512_bf16, dim3(4096), dim3(256), 0, stream,
                           hcur, sru_lng + (size_t)l * 512, sru_lnb + (size_t)l * 512, xnh, xnl);
        hipLaunchKernelGGL(gemm_split, dim3(1536 / 64, M_ / 64), dim3(256), 0, stream,
                           xnh, xnl, swh, swl, U, 1536, 512,
                           (const float*)nullptr, (const float*)nullptr);
        hipLaunchKernelGGL(sru_rec, dim3(128), dim3(64), 0, stream,
                           U, 1536, hcur, sru_wc + (size_t)l * 1024, sru_b + (size_t)l * 1024, hnxt);
        float* tmp = hcur; hcur = hnxt; hnxt = tmp;
    }
    // after 7 layers: hcur == hP

    // ---- LSTM layers 0..2 (gx = [U|hP]; hP dead after its LN; out -> hQ in-place) ----
    for (int l = 0; l < 3; ++l) {
        hipLaunchKernelGGL(conv_split, dim3(4096), dim3(256), 0, stream,
                           lstm_wih + (size_t)l * 2048 * 512, wihh, wihl, 2048 * 512);
        hipLaunchKernelGGL(conv_split, dim3(4096), dim3(256), 0, stream,
                           lstm_whh + (size_t)l * 2048 * 512, whhh, whhl, 2048 * 512);
        hipLaunchKernelGGL(ln512_bf16, dim3(4096), dim3(256), 0, stream,
                           hcur, lstm_lng + (size_t)l * 512, lstm_lnb + (size_t)l * 512, xnh, xnl);
        hipLaunchKernelGGL(gemm_split, dim3(2048 / 64, M_ / 64), dim3(256), 0, stream,
                           xnh, xnl, wihh, wihl, gx, 2048, 512,
                           lstm_bih + (size_t)l * 2048, lstm_bhh + (size_t)l * 2048);
        hipLaunchKernelGGL(lstm_rec, dim3(16), dim3(256), 0, stream,
                           gx, whhh, whhl, hQ, hbuf, flags + l * 64);
        hcur = hQ;
    }
    // ---- classifier ----
    hipLaunchKernelGGL(ln512_f32, dim3(4096), dim3(256), 0, stream, hcur, cls_lng, cls_lnb, (float*)U);
    hipLaunchKernelGGL(cls_gemm, dim3(2048), dim3(256), 0, stream, (const float*)U, cls_w, out);
}

// Round 6
// 15057.153 us; speedup vs baseline: 2.1844x; 1.4751x over previous
//
#include <hip/hip_runtime.h>
#include <stdint.h>
#include <stddef.h>

#define B_ 16
#define T_ 1024
#define F_ 80
#define D_ 512
#define M_ 16384   // T*B rows, row index = t*16 + b
#define VO 29      // V+1
#define SENT 0x7FC07FC0u

typedef float f32x4 __attribute__((ext_vector_type(4)));
typedef short s16x8 __attribute__((ext_vector_type(8)));
typedef unsigned short u16x8 __attribute__((ext_vector_type(8)));

static __device__ __forceinline__ unsigned short f2bf(float f) {
    union { float f; unsigned u; } v; v.f = f;
    unsigned r = v.u + 0x7FFFu + ((v.u >> 16) & 1u);
    return (unsigned short)(r >> 16);
}
static __device__ __forceinline__ float bf2f(unsigned short h) {
    union { unsigned u; float f; } v; v.u = ((unsigned)h) << 16; return v.f;
}
static __device__ __forceinline__ void split2(float v, unsigned short& hi, unsigned short& lo) {
    hi = f2bf(v);
    lo = f2bf(v - bf2f(hi));
}
static __device__ __forceinline__ float sigm(float x) {
    return 1.0f / (1.0f + __expf(-x));
}
static __device__ __forceinline__ float fast_tanh(float x) {
    return 1.0f - 2.0f / (__expf(2.0f * x) + 1.0f);
}
static __device__ __forceinline__ float wred(float v) {
    #pragma unroll
    for (int off = 1; off < 64; off <<= 1) v += __shfl_xor(v, off, 64);
    return v;
}

// ---------------- weight conversion (fp32 -> bf16 hi/lo split) ----------------
__global__ __launch_bounds__(256) void conv_w0(const float* __restrict__ W,
        unsigned short* __restrict__ Bh, unsigned short* __restrict__ Bl) {
    int gid = blockIdx.x * 256 + threadIdx.x;     // 2048*96
    int n = gid / 96, k = gid - n * 96;
    float v = (k < 80) ? W[(size_t)k * 2048 + n] : 0.0f;
    unsigned short h, l; split2(v, h, l);
    Bh[gid] = h; Bl[gid] = l;
}
__global__ __launch_bounds__(256) void conv_sruw1(const float* __restrict__ W,
        unsigned short* __restrict__ Bh, unsigned short* __restrict__ Bl) {
    int gid = blockIdx.x * 256 + threadIdx.x;     // 1536*512
    int n = gid >> 9, k = gid & 511;
    float v = W[(size_t)k * 1536 + n];
    unsigned short h, lo; split2(v, h, lo);
    Bh[gid] = h; Bl[gid] = lo;
}
__global__ __launch_bounds__(256) void conv_split(const float* __restrict__ W,
        unsigned short* __restrict__ Oh, unsigned short* __restrict__ Ol, int n) {
    int gid = blockIdx.x * 256 + threadIdx.x;
    if (gid < n) {
        unsigned short h, l; split2(W[gid], h, l);
        Oh[gid] = h; Ol[gid] = l;
    }
}
// fill 3-phase hbuf with sentinel via agent-scope stores (visible at MALL)
__global__ __launch_bounds__(256) void sent_fill(unsigned int* __restrict__ hbuf) {
    int gid = blockIdx.x * 256 + threadIdx.x;     // 96*256 = 24576
    __hip_atomic_store(&hbuf[gid], SENT, __ATOMIC_RELAXED, __HIP_MEMORY_SCOPE_AGENT);
}

// ---------------- LayerNorm kernels ----------------
__global__ __launch_bounds__(256) void ln80_kernel(const float* __restrict__ x,
        const float* __restrict__ g, const float* __restrict__ bta,
        unsigned short* __restrict__ xh, unsigned short* __restrict__ xl) {
    int w = threadIdx.x >> 6, lane = threadIdx.x & 63;
    int row = blockIdx.x * 4 + w;          // row = t*16 + b
    int b = row & 15, t = row >> 4;
    const float* xr = x + ((size_t)b * T_ + t) * F_;
    float v0 = xr[lane];
    float v1 = (lane < 16) ? xr[64 + lane] : 0.0f;
    float mean = wred(v0 + v1) * (1.0f / 80.0f);
    float d0 = v0 - mean;
    float d1 = (lane < 16) ? (v1 - mean) : 0.0f;
    float var = wred(d0 * d0 + d1 * d1) * (1.0f / 80.0f);
    float rstd = rsqrtf(var + 1e-5f);
    float o0 = d0 * rstd * g[lane] + bta[lane];
    unsigned short h, l; split2(o0, h, l);
    xh[(size_t)row * 96 + lane] = h;
    xl[(size_t)row * 96 + lane] = l;
    if (lane < 32) {
        unsigned short hv = 0, lv = 0;
        if (lane < 16) {
            float o1 = d1 * rstd * g[64 + lane] + bta[64 + lane];
            split2(o1, hv, lv);
        }
        xh[(size_t)row * 96 + 64 + lane] = hv;
        xl[(size_t)row * 96 + 64 + lane] = lv;
    }
}

__global__ __launch_bounds__(256) void ln512_bf16(const float* __restrict__ hsrc,
        const float* __restrict__ g, const float* __restrict__ bta,
        unsigned short* __restrict__ oh, unsigned short* __restrict__ ol) {
    int w = threadIdx.x >> 6, lane = threadIdx.x & 63;
    size_t row = (size_t)blockIdx.x * 4 + w;
    const float* hr = hsrc + row * D_;
    float4 p0 = *(const float4*)(hr + lane * 8);
    float4 p1 = *(const float4*)(hr + lane * 8 + 4);
    float s = p0.x + p0.y + p0.z + p0.w + p1.x + p1.y + p1.z + p1.w;
    float mean = wred(s) * (1.0f / 512.0f);
    float d[8] = {p0.x - mean, p0.y - mean, p0.z - mean, p0.w - mean,
                  p1.x - mean, p1.y - mean, p1.z - mean, p1.w - mean};
    float q = 0.f;
    #pragma unroll
    for (int i = 0; i < 8; ++i) q += d[i] * d[i];
    float rstd = rsqrtf(wred(q) * (1.0f / 512.0f) + 1e-5f);
    const float* gp = g + lane * 8;
    const float* bp = bta + lane * 8;
    u16x8 vh, vl;
    #pragma unroll
    for (int i = 0; i < 8; ++i) {
        float o = d[i] * rstd * gp[i] + bp[i];
        unsigned short hh, ll; split2(o, hh, ll);
        vh[i] = hh; vl[i] = ll;
    }
    *(u16x8*)(oh + row * D_ + lane * 8) = vh;
    *(u16x8*)(ol + row * D_ + lane * 8) = vl;
}

__global__ __launch_bounds__(256) void ln512_f32(const float* __restrict__ hsrc,
        const float* __restrict__ g, const float* __restrict__ bta,
        float* __restrict__ o) {
    int w = threadIdx.x >> 6, lane = threadIdx.x & 63;
    size_t row = (size_t)blockIdx.x * 4 + w;
    const float* hr = hsrc + row * D_;
    float4 p0 = *(const float4*)(hr + lane * 8);
    float4 p1 = *(const float4*)(hr + lane * 8 + 4);
    float s = p0.x + p0.y + p0.z + p0.w + p1.x + p1.y + p1.z + p1.w;
    float mean = wred(s) * (1.0f / 512.0f);
    float d[8] = {p0.x - mean, p0.y - mean, p0.z - mean, p0.w - mean,
                  p1.x - mean, p1.y - mean, p1.z - mean, p1.w - mean};
    float q = 0.f;
    #pragma unroll
    for (int i = 0; i < 8; ++i) q += d[i] * d[i];
    float rstd = rsqrtf(wred(q) * (1.0f / 512.0f) + 1e-5f);
    const float* gp = g + lane * 8;
    const float* bp = bta + lane * 8;
    float* op = o + row * D_ + lane * 8;
    #pragma unroll
    for (int i = 0; i < 8; ++i) op[i] = d[i] * rstd * gp[i] + bp[i];
}

// ------- split bf16 MFMA GEMM (fp32-accurate): C = A * Bt^T (+bias0+bias1) -------
__global__ __launch_bounds__(256) void gemm_split(
        const unsigned short* __restrict__ Ah, const unsigned short* __restrict__ Al,
        const unsigned short* __restrict__ Bh, const unsigned short* __restrict__ Bl,
        float* __restrict__ C, int N, int Kp,
        const float* __restrict__ bias0, const float* __restrict__ bias1) {
    __shared__ __align__(16) unsigned short sAh[64][40];
    __shared__ __align__(16) unsigned short sAl[64][40];
    __shared__ __align__(16) unsigned short sBh[64][40];
    __shared__ __align__(16) unsigned short sBl[64][40];
    int tid = threadIdx.x;
    int w = tid >> 6, lane = tid & 63;
    int r_ = lane >> 4, c_ = lane & 15;
    int mBase = blockIdx.y * 64, nBase = blockIdx.x * 64;
    int srow = tid >> 2, sseg = (tid & 3) * 8;
    const unsigned short* gAh = Ah + (size_t)(mBase + srow) * Kp + sseg;
    const unsigned short* gAl = Al + (size_t)(mBase + srow) * Kp + sseg;
    const unsigned short* gBh = Bh + (size_t)(nBase + srow) * Kp + sseg;
    const unsigned short* gBl = Bl + (size_t)(nBase + srow) * Kp + sseg;
    f32x4 acc[4] = {{0.f,0.f,0.f,0.f},{0.f,0.f,0.f,0.f},{0.f,0.f,0.f,0.f},{0.f,0.f,0.f,0.f}};
    for (int kt = 0; kt < Kp; kt += 32) {
        *(u16x8*)&sAh[srow][sseg] = *(const u16x8*)(gAh + kt);
        *(u16x8*)&sAl[srow][sseg] = *(const u16x8*)(gAl + kt);
        *(u16x8*)&sBh[srow][sseg] = *(const u16x8*)(gBh + kt);
        *(u16x8*)&sBl[srow][sseg] = *(const u16x8*)(gBl + kt);
        __syncthreads();
        s16x8 ah = *(const s16x8*)&sAh[w * 16 + c_][r_ * 8];
        s16x8 al = *(const s16x8*)&sAl[w * 16 + c_][r_ * 8];
        #pragma unroll
        for (int nt = 0; nt < 4; ++nt) {
            s16x8 bh = *(const s16x8*)&sBh[nt * 16 + c_][r_ * 8];
            s16x8 bl = *(const s16x8*)&sBl[nt * 16 + c_][r_ * 8];
            acc[nt] = __builtin_amdgcn_mfma_f32_16x16x32_bf16(ah, bh, acc[nt], 0, 0, 0);
            acc[nt] = __builtin_amdgcn_mfma_f32_16x16x32_bf16(al, bh, acc[nt], 0, 0, 0);
            acc[nt] = __builtin_amdgcn_mfma_f32_16x16x32_bf16(ah, bl, acc[nt], 0, 0, 0);
        }
        __syncthreads();
    }
    #pragma unroll
    for (int r = 0; r < 4; ++r) {
        int m = mBase + w * 16 + r_ * 4 + r;
        float* crow = C + (size_t)m * N + nBase;
        #pragma unroll
        for (int nt = 0; nt < 4; ++nt) {
            int n = nBase + nt * 16 + c_;
            float bb = 0.f;
            if (bias0) bb += bias0[n];
            if (bias1) bb += bias1[n];
            crow[nt * 16 + c_] = acc[nt][r] + bb;
        }
    }
}

// ---------------- SRU recurrence: 8192 independent (b,d) chains ----------------
__global__ __launch_bounds__(64) void sru_rec(const float* __restrict__ U, int NU,
        const float* __restrict__ xprev, const float* __restrict__ wc,
        const float* __restrict__ bias, float* __restrict__ hout) {
    int gid = blockIdx.x * 64 + threadIdx.x;
    int d = gid & (D_ - 1), b = gid >> 9;
    float vf = wc[d], vr = wc[D_ + d];
    float bf = bias[d], br = bias[D_ + d];
    const float* u0 = U + d;
    const float* u1 = U + D_ + d;
    const float* u2 = U + 2 * D_ + d;
    const float* xr;  size_t xstride;
    if (xprev) { xr = xprev + d; xstride = D_; }
    else       { xr = U + 3 * (size_t)D_ + d; xstride = (size_t)NU; }
    float* ho = hout + d;
    float c = 0.f;
    #pragma unroll 4
    for (int t = 0; t < T_; ++t) {
        size_t row = (size_t)(t * 16 + b);
        float a0 = u0[row * NU];
        float a1 = u1[row * NU];
        float a2 = u2[row * NU];
        float xv = xr[row * xstride];
        float f = sigm(a1 + vf * c + bf);
        float r = sigm(a2 + vr * c + br);
        c = f * c + (1.f - f) * a0;
        float h = r * c + (1.f - r) * xv;
        ho[row * D_] = h;
    }
}

// ---------------- LSTM recurrence: 16-WG persistent, NaN-sentinel data polling ----
// Triple-buffered h exchange. Consumers poll the DATA (bf16 of |h|<=1 is never NaN;
// sentinel 0x7FC0 upper-half marks not-yet-written). No flags, no consumer-side
// drains: per step = store transit + poll return (~1.5 RT) + compute.
// Reset-before-write safety: own-slice sentinel resets of buf[(t+1)%3] issued at
// iter top, drained by the mid-step vmcnt(0) BEFORE h_t stores are issued; a
// consumer that saw h_t therefore sees the reset (or newer) in buf[(t+1)%3].
__global__ __launch_bounds__(256, 1) void lstm_rec(const float* __restrict__ gx,
        const unsigned short* __restrict__ Wh, const unsigned short* __restrict__ Wl,
        float* __restrict__ hout,
        unsigned int* __restrict__ hbuf /*3 phases x {hi[4096], lo[4096]}*/) {
    __shared__ __align__(16) unsigned short hH[16][520];
    __shared__ __align__(16) unsigned short hL[16][520];
    __shared__ float G[16][132];
    const int tid = threadIdx.x;
    const int w = tid >> 6, lane = tid & 63;
    const int wg = blockIdx.x;
    const int c_ = lane & 15, r_ = lane >> 4;

    s16x8 bh0[16], bh1[16], bl0[16], bl1[16];
    {
        size_t R0 = (size_t)(w * 512 + wg * 32 + c_) * 512;
        size_t R1 = R0 + 16 * 512;
        #pragma unroll
        for (int ks = 0; ks < 16; ++ks) {
            bh0[ks] = *(const s16x8*)(Wh + R0 + ks * 32 + r_ * 8);
            bh1[ks] = *(const s16x8*)(Wh + R1 + ks * 32 + r_ * 8);
            bl0[ks] = *(const s16x8*)(Wl + R0 + ks * 32 + r_ * 8);
            bl1[ks] = *(const s16x8*)(Wl + R1 + ks * 32 + r_ * 8);
        }
    }
    for (int i = tid; i < 16 * 520; i += 256) {
        ((unsigned short*)hH)[i] = 0;
        ((unsigned short*)hL)[i] = 0;
    }
    const int eb = tid >> 4;
    const int ed = (tid * 2) & 31;
    float cc0 = 0.f, cc1 = 0.f;
    const int col0 = w * 512 + wg * 32 + c_;
    const int hidx = (eb * 512 + wg * 32 + ed) >> 1;   // our dword slot per plane

    float gxv0[4], gxv1[4];
    {
        const float* gxr = gx;
        #pragma unroll
        for (int r = 0; r < 4; ++r) {
            int bt = r_ * 4 + r;
            gxv0[r] = gxr[(size_t)bt * 2048 + col0];
            gxv1[r] = gxr[(size_t)bt * 2048 + col0 + 16];
        }
    }
    int pcur = 0, pnxt = 8192, pthr = 16384;   // rotating phase bases (dword idx)
    __syncthreads();

    for (int t = 0; t < T_; ++t) {
        // reset own slots of the step-(t+1) buffer (drained before h_t stores)
        __hip_atomic_store(&hbuf[pnxt + hidx], SENT, __ATOMIC_RELAXED, __HIP_MEMORY_SCOPE_AGENT);
        __hip_atomic_store(&hbuf[pnxt + 4096 + hidx], SENT, __ATOMIC_RELAXED, __HIP_MEMORY_SCOPE_AGENT);
        // ---- MFMA: gate slice = h_{t-1} @ whh_slice^T (3-term split) ----
        f32x4 acc0 = {0.f, 0.f, 0.f, 0.f};
        f32x4 acc1 = {0.f, 0.f, 0.f, 0.f};
        #pragma unroll
        for (int ks = 0; ks < 16; ++ks) {
            s16x8 ah = *(const s16x8*)&hH[c_][ks * 32 + r_ * 8];
            s16x8 al = *(const s16x8*)&hL[c_][ks * 32 + r_ * 8];
            acc0 = __builtin_amdgcn_mfma_f32_16x16x32_bf16(ah, bh0[ks], acc0, 0, 0, 0);
            acc1 = __builtin_amdgcn_mfma_f32_16x16x32_bf16(ah, bh1[ks], acc1, 0, 0, 0);
            acc0 = __builtin_amdgcn_mfma_f32_16x16x32_bf16(al, bh0[ks], acc0, 0, 0, 0);
            acc1 = __builtin_amdgcn_mfma_f32_16x16x32_bf16(al, bh1[ks], acc1, 0, 0, 0);
            acc0 = __builtin_amdgcn_mfma_f32_16x16x32_bf16(ah, bl0[ks], acc0, 0, 0, 0);
            acc1 = __builtin_amdgcn_mfma_f32_16x16x32_bf16(ah, bl1[ks], acc1, 0, 0, 0);
        }
        #pragma unroll
        for (int r = 0; r < 4; ++r) {
            int bt = r_ * 4 + r;
            G[bt][w * 32 + c_]      = acc0[r] + gxv0[r];
            G[bt][w * 32 + 16 + c_] = acc1[r] + gxv1[r];
        }
        __syncthreads();                                   // G ready, hH free
        // ---- elementwise LSTM cell (2 dims/thread) ----
        float iv0 = G[eb][ed],     fv0 = G[eb][32 + ed], gv0 = G[eb][64 + ed], ov0 = G[eb][96 + ed];
        float iv1 = G[eb][ed + 1], fv1 = G[eb][33 + ed], gv1 = G[eb][65 + ed], ov1 = G[eb][97 + ed];
        cc0 = sigm(fv0) * cc0 + sigm(iv0) * fast_tanh(gv0);
        cc1 = sigm(fv1) * cc1 + sigm(iv1) * fast_tanh(gv1);
        float h0 = sigm(ov0) * fast_tanh(cc0);
        float h1 = sigm(ov1) * fast_tanh(cc1);
        // drain: sentinel resets (and stale loads) reach coherence point BEFORE
        // any h_t store below can be observed
        asm volatile("s_waitcnt vmcnt(0)" ::: "memory");
        unsigned short h0h, h0l, h1h, h1l;
        split2(h0, h0h, h0l); split2(h1, h1h, h1l);
        unsigned packH = (unsigned)h0h | ((unsigned)h1h << 16);
        unsigned packL = (unsigned)h0l | ((unsigned)h1l << 16);
        __hip_atomic_store(&hbuf[pcur + hidx], packH, __ATOMIC_RELAXED, __HIP_MEMORY_SCOPE_AGENT);
        __hip_atomic_store(&hbuf[pcur + 4096 + hidx], packL, __ATOMIC_RELAXED, __HIP_MEMORY_SCOPE_AGENT);
        size_t orow = (size_t)(t * 16 + eb) * D_ + wg * 32 + ed;
        hout[orow] = h0; hout[orow + 1] = h1;
        if (t == T_ - 1) break;                            // no consumer for h_last
        // prefetch gx for t+1 (independent of the exchange)
        {
            const float* gxr = gx + (size_t)((t + 1) * 16) * 2048;
            #pragma unroll
            for (int r = 0; r < 4; ++r) {
                int bt = r_ * 4 + r;
                gxv0[r] = gxr[(size_t)bt * 2048 + col0];
                gxv1[r] = gxr[(size_t)bt * 2048 + col0 + 16];
            }
        }
        // ---- poll the data words of buf[t%3] until fully non-sentinel ----
        unsigned long long vh[8], vl[8];
        while (true) {
            unsigned bad = 0u;
            #pragma unroll
            for (int j = 0; j < 8; ++j) {
                int q = pcur + j * 512 + tid * 2;
                vh[j] = __hip_atomic_load((const unsigned long long*)&hbuf[q],
                                          __ATOMIC_RELAXED, __HIP_MEMORY_SCOPE_AGENT);
                vl[j] = __hip_atomic_load((const unsigned long long*)&hbuf[q + 4096],
                                          __ATOMIC_RELAXED, __HIP_MEMORY_SCOPE_AGENT);
            }
            #pragma unroll
            for (int j = 0; j < 8; ++j) {
                unsigned a0 = (unsigned)vh[j], a1 = (unsigned)(vh[j] >> 32);
                unsigned b0 = (unsigned)vl[j], b1 = (unsigned)(vl[j] >> 32);
                bad |= ((a0 >> 16) == 0x7FC0u) | ((a1 >> 16) == 0x7FC0u)
                     | ((b0 >> 16) == 0x7FC0u) | ((b1 >> 16) == 0x7FC0u);
            }
            if (!__any(bad)) break;
            __builtin_amdgcn_s_sleep(1);
        }
        #pragma unroll
        for (int j = 0; j < 8; ++j) {
            int q = j * 512 + tid * 2;
            int bb = q >> 8, dd = (q & 255) * 2;
            *(unsigned long long*)&hH[bb][dd] = vh[j];
            *(unsigned long long*)&hL[bb][dd] = vl[j];
        }
        __syncthreads();                                   // hH/hL published
        int tmp = pcur; pcur = pnxt; pnxt = pthr; pthr = tmp;
    }
}

// ---------------- classifier ----------------
__global__ __launch_bounds__(256) void cls_gemm(const float* __restrict__ xn,
        const float* __restrict__ wcls, float* __restrict__ out) {
    __shared__ float wl[512][32];
    int tid = threadIdx.x;
    for (int idx = tid; idx < 512 * VO; idx += 256) {
        int k = idx / VO, v = idx - k * VO;
        wl[k][v] = wcls[idx];
    }
    __syncthreads();
    int r8 = tid >> 5, v = tid & 31;
    int row = blockIdx.x * 8 + r8;
    if (v >= VO) return;
    const float* xr = xn + (size_t)row * D_;
    float acc = 0.f;
    #pragma unroll 8
    for (int k = 0; k < 512; ++k) acc += xr[k] * wl[k][v];
    int b = row & 15, t = row >> 4;
    out[((size_t)b * T_ + t) * VO + v] = acc;
}

// ------------------------------- launch ------------------------------------------
extern "C" void kernel_launch(void* const* d_in, const int* in_sizes, int n_in,
                              void* d_out, int out_size, void* d_ws, size_t ws_size,
                              hipStream_t stream) {
    const float* x        = (const float*)d_in[0];
    const float* sru_w0   = (const float*)d_in[1];
    const float* sru_wc0  = (const float*)d_in[2];
    const float* sru_b0   = (const float*)d_in[3];
    const float* sru_ln0g = (const float*)d_in[4];
    const float* sru_ln0b = (const float*)d_in[5];
    const float* sru_w    = (const float*)d_in[6];
    const float* sru_wc   = (const float*)d_in[7];
    const float* sru_b    = (const float*)d_in[8];
    const float* sru_lng  = (const float*)d_in[9];
    const float* sru_lnb  = (const float*)d_in[10];
    const float* lstm_lng = (const float*)d_in[11];
    const float* lstm_lnb = (const float*)d_in[12];
    const float* lstm_wih = (const float*)d_in[13];
    const float* lstm_whh = (const float*)d_in[14];
    const float* lstm_bih = (const float*)d_in[15];
    const float* lstm_bhh = (const float*)d_in[16];
    const float* cls_lng  = (const float*)d_in[17];
    const float* cls_lnb  = (const float*)d_in[18];
    const float* cls_w    = (const float*)d_in[19];
    float* out = (float*)d_out;

    char* ws = (char*)d_ws;
    size_t off = 0;
    auto alloc = [&](size_t bytes) -> void* {
        off = (off + 255) & ~(size_t)255;
        void* p = ws + off;
        off += bytes;
        return p;
    };
    float* U             = (float*)alloc((size_t)M_ * 1536 * 4);
    float* hP            = (float*)alloc((size_t)M_ * D_ * 4);     // contiguous after U
    float* hQ            = (float*)alloc((size_t)M_ * D_ * 4);
    unsigned short* xnh  = (unsigned short*)alloc((size_t)M_ * D_ * 2);
    unsigned short* xnl  = (unsigned short*)alloc((size_t)M_ * D_ * 2);
    unsigned short* w0h  = (unsigned short*)alloc((size_t)2048 * 96 * 2);
    unsigned short* w0l  = (unsigned short*)alloc((size_t)2048 * 96 * 2);
    unsigned short* swh  = (unsigned short*)alloc((size_t)1536 * 512 * 2);  // per-layer reuse
    unsigned short* swl  = (unsigned short*)alloc((size_t)1536 * 512 * 2);
    unsigned short* wihh = (unsigned short*)alloc((size_t)2048 * 512 * 2);  // per-layer reuse
    unsigned short* wihl = (unsigned short*)alloc((size_t)2048 * 512 * 2);
    unsigned short* whhh = (unsigned short*)alloc((size_t)2048 * 512 * 2);  // per-layer reuse
    unsigned short* whhl = (unsigned short*)alloc((size_t)2048 * 512 * 2);
    unsigned int* hbuf   = (unsigned int*)alloc((size_t)3 * 2 * 4096 * 4); // 3-phase
    float* gx = U;   // 2048-wide outputs span [U | hP] contiguously

    hipLaunchKernelGGL(conv_w0, dim3(768), dim3(256), 0, stream, sru_w0, w0h, w0l);

    // ---- SRU layer 0 (gx = [U|hP], output -> hQ) ----
    hipLaunchKernelGGL(ln80_kernel, dim3(4096), dim3(256), 0, stream, x, sru_ln0g, sru_ln0b, xnh, xnl);
    hipLaunchKernelGGL(gemm_split, dim3(2048 / 64, M_ / 64), dim3(256), 0, stream,
                       xnh, xnl, w0h, w0l, gx, 2048, 96, (const float*)nullptr, (const float*)nullptr);
    hipLaunchKernelGGL(sru_rec, dim3(128), dim3(64), 0, stream,
                       gx, 2048, (const float*)nullptr, sru_wc0, sru_b0, hQ);

    float* hcur = hQ; float* hnxt = hP;
    // ---- SRU layers 1..7 (GEMM writes U only; h ping-pongs hQ<->hP) ----
    for (int l = 0; l < 7; ++l) {
        hipLaunchKernelGGL(conv_sruw1, dim3(3072), dim3(256), 0, stream,
                           sru_w + (size_t)l * 512 * 1536, swh, swl);
        hipLaunchKernelGGL(ln512_bf16, dim3(4096), dim3(256), 0, stream,
                           hcur, sru_lng + (size_t)l * 512, sru_lnb + (size_t)l * 512, xnh, xnl);
        hipLaunchKernelGGL(gemm_split, dim3(1536 / 64, M_ / 64), dim3(256), 0, stream,
                           xnh, xnl, swh, swl, U, 1536, 512,
                           (const float*)nullptr, (const float*)nullptr);
        hipLaunchKernelGGL(sru_rec, dim3(128), dim3(64), 0, stream,
                           U, 1536, hcur, sru_wc + (size_t)l * 1024, sru_b + (size_t)l * 1024, hnxt);
        float* tmp = hcur; hcur = hnxt; hnxt = tmp;
    }
    // after 7 layers: hcur == hP

    // ---- LSTM layers 0..2 (gx = [U|hP]; hP dead after its LN; out -> hQ in-place) ----
    for (int l = 0; l < 3; ++l) {
        hipLaunchKernelGGL(conv_split, dim3(4096), dim3(256), 0, stream,
                           lstm_wih + (size_t)l * 2048 * 512, wihh, wihl, 2048 * 512);
        hipLaunchKernelGGL(conv_split, dim3(4096), dim3(256), 0, stream,
                           lstm_whh + (size_t)l * 2048 * 512, whhh, whhl, 2048 * 512);
        hipLaunchKernelGGL(ln512_bf16, dim3(4096), dim3(256), 0, stream,
                           hcur, lstm_lng + (size_t)l * 512, lstm_lnb + (size_t)l * 512, xnh, xnl);
        hipLaunchKernelGGL(gemm_split, dim3(2048 / 64, M_ / 64), dim3(256), 0, stream,
                           xnh, xnl, wihh, wihl, gx, 2048, 512,
                           lstm_bih + (size_t)l * 2048, lstm_bhh + (size_t)l * 2048);
        hipLaunchKernelGGL(sent_fill, dim3(96), dim3(256), 0, stream, hbuf);
        hipLaunchKernelGGL(lstm_rec, dim3(16), dim3(256), 0, stream,
                           gx, whhh, whhl, hQ, hbuf);
        hcur = hQ;
    }
    // ---- classifier ----
    hipLaunchKernelGGL(ln512_f32, dim3(4096), dim3(256), 0, stream, hcur, cls_lng, cls_lnb, (float*)U);
    hipLaunchKernelGGL(cls_gemm, dim3(2048), dim3(256), 0, stream, (const float*)U, cls_w, out);
}